// Round 12
// baseline (2728.482 us; speedup 1.0000x reference)
//
#include <hip/hip_runtime.h>
#include <math.h>

#define IMG   128
#define Hdim  768
#define Edim  1536
#define Ltok  256
#define PDim  192
#define NLAY  24
#define Bsz   16
#define Mrows 4096          // B * L
#define UVW   3328          // 2E + 2K

typedef __bf16 bf16x8 __attribute__((ext_vector_type(8)));
typedef float  f32x4  __attribute__((ext_vector_type(4)));

__device__ __forceinline__ unsigned short f2b(float f) {
    unsigned int u = __float_as_uint(f);
    unsigned int r = (u + 0x7FFF + ((u >> 16) & 1)) >> 16;
    return (unsigned short)r;
}
__device__ __forceinline__ float b2f(unsigned short s) {
    return __uint_as_float((unsigned int)s << 16);
}
__device__ __forceinline__ unsigned int pk2(float lo, float hi) {
    return (unsigned int)f2b(lo) | ((unsigned int)f2b(hi) << 16);
}
__device__ __forceinline__ float silu(float x) {
    return x / (1.0f + expf(-x));
}
__device__ __forceinline__ void gload16(const void* g, void* l) {
    __builtin_amdgcn_global_load_lds(
        (const __attribute__((address_space(1))) void*)g,
        (__attribute__((address_space(3))) void*)l, 16, 0, 0);
}
// bijective XCD-chunking remap (m204)
__device__ __forceinline__ int xcd_wg() {
    int nwg = gridDim.x;
    int orig = blockIdx.x;
    int q8 = nwg >> 3, r8 = nwg & 7;
    int xcd = orig & 7, loc = orig >> 3;
    return (xcd < r8 ? xcd * (q8 + 1) : r8 * (q8 + 1) + (xcd - r8) * q8) + loc;
}

// ---------------- RoPE table ----------------
__global__ void pe_kernel(float* __restrict__ pe) {
    int l = blockIdx.x;
    int j = threadIdx.x;
    const float c = -logf(1000.0f) / 31.0f;
    int   sub = j & 31;
    float f   = expf(c * (float)sub);
    float pos = (j < 64) ? (float)(l >> 4) : (float)(l & 15);
    float ang = pos * f;
    pe[l * 128 + j] = ((j & 32) == 0) ? sinf(ang) : cosf(ang);
}

// ---------------- patchify -> bf16 ----------------
__global__ void patchify_kernel(const float* __restrict__ x, unsigned short* __restrict__ xp) {
    int bc = blockIdx.x;
    int iy = bc & 127;
    int t  = bc >> 7;
    int c  = t % 3;
    int b  = t / 3;
    int ix = threadIdx.x;
    float v = x[((size_t)(b * 3 + c) * IMG + iy) * IMG + ix];
    int gy = iy >> 3, py = iy & 7, gx = ix >> 3, px = ix & 7;
    xp[(size_t)(b * Ltok + gy * 16 + gx) * PDim + (py * 8 + px) * 3 + c] = f2b(v);
}

// ---------------- fp32 [R][C] -> bf16 transposed [C][R] ----------------
__global__ void trans_kernel(const float* __restrict__ src, int ldS, long long sS,
                             unsigned short* __restrict__ dst, int ldD, long long sD) {
    src += (long long)blockIdx.z * sS;
    dst += (long long)blockIdx.z * sD;
    __shared__ float t[32][33];
    int c0 = blockIdx.x * 32, r0 = blockIdx.y * 32;
    int tx = threadIdx.x, ty = threadIdx.y;   // (32,8)
#pragma unroll
    for (int i = 0; i < 4; ++i)
        t[ty + 8 * i][tx] = src[(size_t)(r0 + ty + 8 * i) * ldS + c0 + tx];
    __syncthreads();
#pragma unroll
    for (int i = 0; i < 4; ++i)
        dst[(size_t)(c0 + ty + 8 * i) * ldD + r0 + tx] = f2b(t[tx][ty + 8 * i]);
}

// ================= generic bf16 MFMA GEMM, double-buffered, XCD-swizzled ====
template <int ACC>
__launch_bounds__(256)
__global__ void gemm_bf16(const unsigned short* __restrict__ A, int lda,
                          const unsigned short* __restrict__ Bt, int ldb,
                          float* __restrict__ C, int ldc,
                          int Kt, int Nt, int nbx) {
    __shared__ unsigned short lsA[2][4096];
    __shared__ unsigned short lsB[2][4096];
    int wg = xcd_wg();
    int bx = wg % nbx, by = wg / nbx;
    int tid  = threadIdx.x;
    int lane = tid & 63, w = tid >> 6, wr = w >> 1, wc = w & 1;
    int row0 = by * 128, col0 = bx * 128;
    int fr = lane & 15, fk = (lane >> 4) * 8;
    f32x4 acc[4][4] = {};

    int c0 = tid, c1 = tid + 256;
    int ar0 = row0 + (c0 >> 2), ar1 = row0 + (c1 >> 2);
    int bn0 = col0 + (c0 >> 2), bn1 = col0 + (c1 >> 2);
    if (bn0 > Nt - 1) bn0 = Nt - 1;
    if (bn1 > Nt - 1) bn1 = Nt - 1;
    int ka0 = (c0 & 3) * 8, ka1 = (c1 & 3) * 8;

#define STAGE_G(buf, k0)                                                       \
    gload16(A  + (size_t)ar0 * lda + (k0) + ka0, &lsA[buf][c0 * 8]);           \
    gload16(A  + (size_t)ar1 * lda + (k0) + ka1, &lsA[buf][c1 * 8]);           \
    gload16(Bt + (size_t)bn0 * ldb + (k0) + ka0, &lsB[buf][c0 * 8]);           \
    gload16(Bt + (size_t)bn1 * ldb + (k0) + ka1, &lsB[buf][c1 * 8]);

    STAGE_G(0, 0);
    __syncthreads();
    int nt = Kt >> 5, cur = 0;
    for (int t = 0; t < nt; ++t) {
        if (t + 1 < nt) { STAGE_G(cur ^ 1, (t + 1) * 32); }
        bf16x8 af[4], bfr[4];
#pragma unroll
        for (int m = 0; m < 4; ++m)
            af[m] = *(const bf16x8*)(&lsA[cur][(wr * 64 + m * 16 + fr) * 32 + fk]);
#pragma unroll
        for (int n = 0; n < 4; ++n)
            bfr[n] = *(const bf16x8*)(&lsB[cur][(wc * 64 + n * 16 + fr) * 32 + fk]);
#pragma unroll
        for (int m = 0; m < 4; ++m)
#pragma unroll
            for (int n = 0; n < 4; ++n)
                acc[m][n] = __builtin_amdgcn_mfma_f32_16x16x32_bf16(af[m], bfr[n], acc[m][n], 0, 0, 0);
        __syncthreads();
        cur ^= 1;
    }
#undef STAGE_G

    int crow = (lane >> 4) * 4;
#pragma unroll
    for (int m = 0; m < 4; ++m) {
#pragma unroll
        for (int n = 0; n < 4; ++n) {
            int gc = col0 + wc * 64 + n * 16 + fr;
            if (gc >= Nt) continue;
#pragma unroll
            for (int j = 0; j < 4; ++j) {
                size_t idx = (size_t)(row0 + wr * 64 + m * 16 + crow + j) * ldc + gc;
                if (ACC) C[idx] += acc[m][n][j];
                else     C[idx]  = acc[m][n][j];
            }
        }
    }
}

// ================= wout GEMM, split-K=2, bf16 partials, coalesced stores =====
// A = o_bf [4096][1536], Bt = WoutT_l [768][1536]. grid 384: sk|by|bx.
__launch_bounds__(256)
__global__ void gemm_wout(const unsigned short* __restrict__ A,
                          const unsigned short* __restrict__ Bt,
                          unsigned short* __restrict__ P) {
    __shared__ char smw[32768];
    unsigned short (*lsA)[4096] = (unsigned short (*)[4096])smw;
    unsigned short (*lsB)[4096] = (unsigned short (*)[4096])(smw + 16384);
    int wg = xcd_wg();
    int sk = wg / 192, rem = wg % 192;
    int bx = rem % 6, by = rem / 6;
    int koff = sk * 768;
    unsigned short* C = P + (size_t)sk * Mrows * Hdim;
    int tid  = threadIdx.x;
    int lane = tid & 63, w = tid >> 6, wr = w >> 1, wc = w & 1;
    int row0 = by * 128, col0 = bx * 128;
    int fr = lane & 15, fk = (lane >> 4) * 8;
    f32x4 acc[4][4] = {};

    int c0 = tid, c1 = tid + 256;
    int ar0 = row0 + (c0 >> 2), ar1 = row0 + (c1 >> 2);
    int bn0 = col0 + (c0 >> 2), bn1 = col0 + (c1 >> 2);
    int ka0 = koff + (c0 & 3) * 8, ka1 = koff + (c1 & 3) * 8;

#define STAGE_W(buf, k0)                                                       \
    gload16(A  + (size_t)ar0 * Edim + (k0) + ka0, &lsA[buf][c0 * 8]);          \
    gload16(A  + (size_t)ar1 * Edim + (k0) + ka1, &lsA[buf][c1 * 8]);          \
    gload16(Bt + (size_t)bn0 * Edim + (k0) + ka0, &lsB[buf][c0 * 8]);          \
    gload16(Bt + (size_t)bn1 * Edim + (k0) + ka1, &lsB[buf][c1 * 8]);

    STAGE_W(0, 0);
    __syncthreads();
    int cur = 0;
    for (int t = 0; t < 24; ++t) {
        if (t + 1 < 24) { STAGE_W(cur ^ 1, (t + 1) * 32); }
        bf16x8 af[4], bfr[4];
#pragma unroll
        for (int m = 0; m < 4; ++m)
            af[m] = *(const bf16x8*)(&lsA[cur][(wr * 64 + m * 16 + fr) * 32 + fk]);
#pragma unroll
        for (int n = 0; n < 4; ++n)
            bfr[n] = *(const bf16x8*)(&lsB[cur][(wc * 64 + n * 16 + fr) * 32 + fk]);
#pragma unroll
        for (int m = 0; m < 4; ++m)
#pragma unroll
            for (int n = 0; n < 4; ++n)
                acc[m][n] = __builtin_amdgcn_mfma_f32_16x16x32_bf16(af[m], bfr[n], acc[m][n], 0, 0, 0);
        __syncthreads();
        cur ^= 1;
    }
#undef STAGE_W

    // ---- stage bf16 tile [m_l 128][n_l 128] in LDS, then 256B-row stores ----
    int crow = (lane >> 4) * 4;
    __syncthreads();
#pragma unroll
    for (int m = 0; m < 4; ++m) {
#pragma unroll
        for (int n = 0; n < 4; ++n) {
            int n_l = wc * 64 + n * 16 + fr;
#pragma unroll
            for (int j = 0; j < 4; ++j) {
                int m_l = wr * 64 + m * 16 + crow + j;
                int byte = (m_l * 256 + n_l * 2) ^ ((m_l & 7) << 4);
                *(unsigned short*)(smw + byte) = f2b(acc[m][n][j]);
            }
        }
    }
    __syncthreads();
    int grp = tid >> 4, l16 = tid & 15;
#pragma unroll
    for (int it = 0; it < 8; ++it) {
        int r = it * 16 + grp;
        int byte = (r * 256 + l16 * 16) ^ ((r & 7) << 4);
        int4 v = *(const int4*)(smw + byte);
        *(int4*)(C + (size_t)(row0 + r) * Hdim + col0 + l16 * 8) = v;
    }
}

// ================= uvqk GEMM: 256x256 tile, 8-phase counted-vmcnt pipeline ===
// A = xn [4096][768], Bt = WuvT_l [3328][768]. Grid 208 = 13 bx * 16 by, 512 thr.
// col-tiles 0-5: silu -> u_bf [m][e] (row-major); 6-11: silu -> vT [e][l];
// 12: rope -> qh/kh. All epilogues LDS-coalesced.
__global__ __launch_bounds__(512, 2)
void gemm_uvqk8(const unsigned short* __restrict__ A,
                const unsigned short* __restrict__ Bt,
                unsigned short* __restrict__ u_bf,
                unsigned short* __restrict__ vT,
                unsigned short* __restrict__ qh,
                unsigned short* __restrict__ kh,
                const float* __restrict__ pe) {
    __shared__ char smem[131072];   // 2 bufs * (A 2x16KB + B 2x16KB)
    int wg = xcd_wg();
    int bx = wg % 13, by = wg / 13;
    int tid = threadIdx.x, lane = tid & 63, wid = tid >> 6;
    int wm = wid >> 2, wn = wid & 3;            // 2 x 4 wave grid
    int row0 = by * 256, col0 = bx * 256;
    int fr = lane & 15, hi = lane >> 4;
    f32x4 acc[8][4] = {};

    // ---- staging: linear LDS dest, pre-swizzled global source ----
    int d0 = tid * 16, d1 = d0 + 8192;
    int s0 = d0 ^ (((d0 >> 7) & 7) << 4);
    int s1 = d1 ^ (((d1 >> 7) & 7) << 4);
    int sr0 = s0 >> 7, sc0 = (s0 & 127) >> 1;
    int sr1 = s1 >> 7, sc1 = (s1 & 127) >> 1;

#define STG_A(bufo, h, kt) do {                                                            \
    gload16(A + (size_t)(row0 + (h) * 128 + sr0) * Hdim + (kt) * 64 + sc0,                 \
            smem + (bufo) + (h) * 16384 + d0);                                             \
    gload16(A + (size_t)(row0 + (h) * 128 + sr1) * Hdim + (kt) * 64 + sc1,                 \
            smem + (bufo) + (h) * 16384 + d1); } while (0)
#define STG_B(bufo, h, kt) do {                                                            \
    gload16(Bt + (size_t)(col0 + (h) * 128 + sr0) * Hdim + (kt) * 64 + sc0,                \
            smem + (bufo) + 32768 + (h) * 16384 + d0);                                     \
    gload16(Bt + (size_t)(col0 + (h) * 128 + sr1) * Hdim + (kt) * 64 + sc1,                \
            smem + (bufo) + 32768 + (h) * 16384 + d1); } while (0)

    // ---- ds_read fragment addressing (swizzled) ----
    int axor = (fr & 7) << 4;
    int abase = wm * 16384 + fr * 128;
    int bbase = 32768 + (wn >> 1) * 16384 + ((wn & 1) * 64 + fr) * 128;
    int koff0 = (hi * 16) ^ axor;
    int koff1 = (hi * 16 + 64) ^ axor;

    // ---- prologue: kt0 (all 4 halves) + kt1 A-halves ----
    STG_A(0, 0, 0); STG_A(0, 1, 0); STG_B(0, 0, 0); STG_B(0, 1, 0);
    STG_A(65536, 0, 1); STG_A(65536, 1, 1);
    asm volatile("s_waitcnt vmcnt(4)" ::: "memory");
    __builtin_amdgcn_s_barrier();
    __builtin_amdgcn_sched_barrier(0);

    bf16x8 af[4][2], bf0[2][2], bf1[2][2];
    const int NKT = Hdim / 64;   // 12
    for (int kt = 0; kt < NKT; ++kt) {
        int curo = (kt & 1) << 16, nxto = curo ^ 65536;
        const char* bufc = smem + curo;

        // ---- phase 0: (mh0, nh0) ----
#pragma unroll
        for (int m = 0; m < 4; ++m) {
            af[m][0] = *(const bf16x8*)(bufc + abase + m * 2048 + koff0);
            af[m][1] = *(const bf16x8*)(bufc + abase + m * 2048 + koff1);
        }
#pragma unroll
        for (int n = 0; n < 2; ++n) {
            bf0[n][0] = *(const bf16x8*)(bufc + bbase + n * 2048 + koff0);
            bf0[n][1] = *(const bf16x8*)(bufc + bbase + n * 2048 + koff1);
        }
        if (kt + 1 < NKT) STG_B(nxto, 0, kt + 1);
        __builtin_amdgcn_s_setprio(1);
#pragma unroll
        for (int m = 0; m < 4; ++m)
#pragma unroll
            for (int n = 0; n < 2; ++n) {
                acc[m][n] = __builtin_amdgcn_mfma_f32_16x16x32_bf16(af[m][0], bf0[n][0], acc[m][n], 0, 0, 0);
                acc[m][n] = __builtin_amdgcn_mfma_f32_16x16x32_bf16(af[m][1], bf0[n][1], acc[m][n], 0, 0, 0);
            }
        __builtin_amdgcn_s_setprio(0);
        __builtin_amdgcn_s_barrier();
        __builtin_amdgcn_sched_barrier(0);

        // ---- phase 1: (mh0, nh1) ----
#pragma unroll
        for (int n = 0; n < 2; ++n) {
            bf1[n][0] = *(const bf16x8*)(bufc + bbase + (n + 2) * 2048 + koff0);
            bf1[n][1] = *(const bf16x8*)(bufc + bbase + (n + 2) * 2048 + koff1);
        }
        if (kt + 1 < NKT) STG_B(nxto, 1, kt + 1);
        __builtin_amdgcn_s_setprio(1);
#pragma unroll
        for (int m = 0; m < 4; ++m)
#pragma unroll
            for (int n = 0; n < 2; ++n) {
                acc[m][n + 2] = __builtin_amdgcn_mfma_f32_16x16x32_bf16(af[m][0], bf1[n][0], acc[m][n + 2], 0, 0, 0);
                acc[m][n + 2] = __builtin_amdgcn_mfma_f32_16x16x32_bf16(af[m][1], bf1[n][1], acc[m][n + 2], 0, 0, 0);
            }
        __builtin_amdgcn_s_setprio(0);
        __builtin_amdgcn_s_barrier();
        __builtin_amdgcn_sched_barrier(0);

        // ---- phase 2: (mh1, nh0) ----
#pragma unroll
        for (int m = 0; m < 4; ++m) {
            af[m][0] = *(const bf16x8*)(bufc + abase + (m + 4) * 2048 + koff0);
            af[m][1] = *(const bf16x8*)(bufc + abase + (m + 4) * 2048 + koff1);
        }
        __builtin_amdgcn_s_setprio(1);
#pragma unroll
        for (int m = 0; m < 4; ++m)
#pragma unroll
            for (int n = 0; n < 2; ++n) {
                acc[m + 4][n] = __builtin_amdgcn_mfma_f32_16x16x32_bf16(af[m][0], bf0[n][0], acc[m + 4][n], 0, 0, 0);
                acc[m + 4][n] = __builtin_amdgcn_mfma_f32_16x16x32_bf16(af[m][1], bf0[n][1], acc[m + 4][n], 0, 0, 0);
            }
        __builtin_amdgcn_s_setprio(0);
        __builtin_amdgcn_s_barrier();
        __builtin_amdgcn_sched_barrier(0);

        // ---- phase 3: (mh1, nh1) ----
        if (kt + 2 < NKT) { STG_A(curo, 0, kt + 2); STG_A(curo, 1, kt + 2); }
        __builtin_amdgcn_s_setprio(1);
#pragma unroll
        for (int m = 0; m < 4; ++m)
#pragma unroll
            for (int n = 0; n < 2; ++n) {
                acc[m + 4][n + 2] = __builtin_amdgcn_mfma_f32_16x16x32_bf16(af[m][0], bf1[n][0], acc[m + 4][n + 2], 0, 0, 0);
                acc[m + 4][n + 2] = __builtin_amdgcn_mfma_f32_16x16x32_bf16(af[m][1], bf1[n][1], acc[m + 4][n + 2], 0, 0, 0);
            }
        __builtin_amdgcn_s_setprio(0);
        asm volatile("s_waitcnt vmcnt(4)" ::: "memory");
        __builtin_amdgcn_s_barrier();
        __builtin_amdgcn_sched_barrier(0);
    }
#undef STG_A
#undef STG_B

    // ================= epilogue =================
    if (bx == 12) {
        // rope: 4 passes of 64 rows through LDS (fp32), q cols 0-127, k 128-255
        float* S = (float*)smem;
        const float qscale = 0.08838834764831845f;   // 128^-0.5
#pragma unroll
        for (int p = 0; p < 4; ++p) {
            __syncthreads();
            if (wm == (p >> 1)) {
#pragma unroll
                for (int m = 0; m < 4; ++m) {
                    int mf = (p & 1) * 4 + m;
                    int rl = m * 16 + hi * 4;
#pragma unroll
                    for (int n = 0; n < 4; ++n) {
                        int cl = wn * 64 + n * 16 + fr;
#pragma unroll
                        for (int j = 0; j < 4; ++j)
                            S[(rl + j) * 256 + cl] = acc[mf][n][j];
                    }
                }
            }
            __syncthreads();
            int r = tid >> 3;
            int dbase = (tid & 7) * 8;
            int row_g = row0 + p * 64 + r;
            int l = row_g & 255;
#pragma unroll
            for (int i = 0; i < 8; ++i) {
                int d = dbase + i;
                float sn = pe[l * 128 + d], cs = pe[l * 128 + 64 + d];
                float q1 = S[r * 256 + d],       q2 = S[r * 256 + d + 64];
                float k1 = S[r * 256 + d + 128], k2 = S[r * 256 + d + 192];
                qh[(size_t)row_g * 128 + d]      = f2b((q1 * cs - q2 * sn) * qscale);
                qh[(size_t)row_g * 128 + d + 64] = f2b((q2 * cs + q1 * sn) * qscale);
                kh[(size_t)row_g * 128 + d]      = f2b(k1 * cs - k2 * sn);
                kh[(size_t)row_g * 128 + d + 64] = f2b(k2 * cs + k1 * sn);
            }
        }
        return;
    }

    __syncthreads();
    if (bx < 6) {
        // ---- u: stage bf16 [m_l 256][e_l 256] (512B rows), coalesced row stores ----
#pragma unroll
        for (int mf = 0; mf < 8; ++mf) {
            int m0 = wm * 128 + mf * 16 + hi * 4;
#pragma unroll
            for (int nf = 0; nf < 4; ++nf) {
                int e_l = wn * 64 + nf * 16 + fr;
#pragma unroll
                for (int j = 0; j < 4; ++j) {
                    int m_l = m0 + j;
                    int byte = (m_l * 512 + e_l * 2) ^ ((m_l & 7) << 4);
                    *(unsigned short*)(smem + byte) = f2b(silu(acc[mf][nf][j]));
                }
            }
        }
        __syncthreads();
        int grp = tid >> 5, l32 = tid & 31;
#pragma unroll
        for (int it = 0; it < 16; ++it) {
            int r = it * 16 + grp;
            int byte = (r * 512 + l32 * 16) ^ ((r & 7) << 4);
            int4 v = *(const int4*)(smem + byte);
            *(int4*)(u_bf + (size_t)(row0 + r) * Edim + bx * 256 + l32 * 8) = v;
        }
        return;
    }

    // ---- v: stage bf16 [e_l 256][m_l 256] transpose, coalesced row stores ----
#pragma unroll
    for (int mf = 0; mf < 8; ++mf) {
        int m_l = wm * 128 + mf * 16 + hi * 4;
#pragma unroll
        for (int nf = 0; nf < 4; ++nf) {
            int e_l = wn * 64 + nf * 16 + fr;
            ushort4 pk;
            pk.x = f2b(silu(acc[mf][nf][0]));
            pk.y = f2b(silu(acc[mf][nf][1]));
            pk.z = f2b(silu(acc[mf][nf][2]));
            pk.w = f2b(silu(acc[mf][nf][3]));
            int byte = (e_l * 512 + m_l * 2) ^ ((e_l & 7) << 4);
            *(ushort4*)(smem + byte) = pk;
        }
    }
    __syncthreads();
    int er = tid >> 5, ch = (tid & 31) * 16;
#pragma unroll
    for (int it = 0; it < 16; ++it) {
        int e_l = it * 16 + er;
        int byte = (e_l * 512 + ch) ^ ((e_l & 7) << 4);
        int4 v = *(const int4*)(smem + byte);
        int e = col0 + e_l - Edim;
        unsigned short* dst = vT + ((size_t)(row0 >> 8) * Edim + e) * Ltok;
        *(int4*)((char*)dst + ch) = v;
    }
}

// ================= fused attention: softmax(q̂k̂ᵀ) @ V ⊙ u -> o_bf =================
// grid (ec=8, qt=4, b=16). O staged fp32 in LDS; u-mul + store coalesced.
__launch_bounds__(256)
__global__ void fused_attn(const unsigned short* __restrict__ qh,
                           const unsigned short* __restrict__ kh,
                           const unsigned short* __restrict__ vT,
                           const unsigned short* __restrict__ u_bf,
                           unsigned short* __restrict__ ob) {
    __shared__ float S[64 * 196];
    int ec = blockIdx.x, qt = blockIdx.y, b = blockIdx.z;
    int tid  = threadIdx.x;
    int lane = tid & 63, w = tid >> 6;
    int fr = lane & 15, hi = lane >> 4;
    int qbase = b * 256 + qt * 64 + w * 16;

    bf16x8 qf[4];
#pragma unroll
    for (int ks = 0; ks < 4; ++ks)
        qf[ks] = *(const bf16x8*)(qh + (size_t)(qbase + fr) * 128 + ks * 32 + hi * 8);
    f32x4 sacc[16] = {};
#pragma unroll
    for (int mf = 0; mf < 16; ++mf) {
#pragma unroll
        for (int ks = 0; ks < 4; ++ks) {
            bf16x8 kf = *(const bf16x8*)(kh + (size_t)(b * 256 + mf * 16 + fr) * 128 + ks * 32 + hi * 8);
            sacc[mf] = __builtin_amdgcn_mfma_f32_16x16x32_bf16(kf, qf[ks], sacc[mf], 0, 0, 0);
        }
    }

    float mx = -3.4e38f;
#pragma unroll
    for (int mf = 0; mf < 16; ++mf)
#pragma unroll
        for (int j = 0; j < 4; ++j)
            mx = fmaxf(mx, sacc[mf][j]);
    mx = fmaxf(mx, __shfl_xor(mx, 16, 64));
    mx = fmaxf(mx, __shfl_xor(mx, 32, 64));
    float sum = 0.f;
#pragma unroll
    for (int mf = 0; mf < 16; ++mf)
#pragma unroll
        for (int j = 0; j < 4; ++j) {
            float e = expf(sacc[mf][j] - mx);
            sacc[mf][j] = e;
            sum += e;
        }
    sum += __shfl_xor(sum, 16, 64);
    sum += __shfl_xor(sum, 32, 64);
    float inv = 1.0f / sum;

    unsigned int dw[16][2];
#pragma unroll
    for (int mf = 0; mf < 16; ++mf) {
        dw[mf][0] = pk2(sacc[mf][0] * inv, sacc[mf][1] * inv);
        dw[mf][1] = pk2(sacc[mf][2] * inv, sacc[mf][3] * inv);
    }

    int sA = fr + 32 * (hi & 1);
    int sB = sA + 16;
    bool up = (hi >> 1) != 0;
    unsigned int pa[8][4];
#pragma unroll
    for (int ks = 0; ks < 8; ++ks) {
        unsigned int a00 = __shfl((int)dw[2 * ks][0],     sA, 64);
        unsigned int a01 = __shfl((int)dw[2 * ks + 1][0], sA, 64);
        unsigned int a10 = __shfl((int)dw[2 * ks][1],     sA, 64);
        unsigned int a11 = __shfl((int)dw[2 * ks + 1][1], sA, 64);
        unsigned int b00 = __shfl((int)dw[2 * ks][0],     sB, 64);
        unsigned int b01 = __shfl((int)dw[2 * ks + 1][0], sB, 64);
        unsigned int b10 = __shfl((int)dw[2 * ks][1],     sB, 64);
        unsigned int b11 = __shfl((int)dw[2 * ks + 1][1], sB, 64);
        pa[ks][0] = up ? a01 : a00;
        pa[ks][1] = up ? a11 : a10;
        pa[ks][2] = up ? b01 : b00;
        pa[ks][3] = up ? b11 : b10;
    }

    // ---- PV: stage O (fp32) into LDS ----
    const unsigned short* vb = vT + (size_t)b * Edim * Ltok;
    int e0 = ec * 192;
    int rb = w * 16 + hi * 4;
#pragma unroll 2
    for (int ef = 0; ef < 12; ++ef) {
        int e = e0 + ef * 16 + fr;
        f32x4 oacc = {};
#pragma unroll
        for (int ks = 0; ks < 8; ++ks) {
            bf16x8 vf = *(const bf16x8*)(vb + (size_t)e * Ltok + ks * 32 + hi * 8);
            oacc = __builtin_amdgcn_mfma_f32_16x16x32_bf16(*(const bf16x8*)&pa[ks], vf, oacc, 0, 0, 0);
        }
        int el = ef * 16 + fr;
        S[(rb + 0) * 196 + el] = oacc[0];
        S[(rb + 1) * 196 + el] = oacc[1];
        S[(rb + 2) * 196 + el] = oacc[2];
        S[(rb + 3) * 196 + el] = oacc[3];
    }
    __syncthreads();

    // ---- u-mul + coalesced store: thread = (row r, quarter q) ----
    int r = tid >> 2, q = tid & 3;
    size_t grow = (size_t)(b * 256 + qt * 64 + r);
    const unsigned short* upv = u_bf + grow * Edim + e0 + q * 48;
    unsigned short* opv = ob + grow * Edim + e0 + q * 48;
    const float* Sr = S + r * 196 + q * 48;
#pragma unroll
    for (int i = 0; i < 6; ++i) {
        float4 a = *(const float4*)(Sr + i * 8);
        float4 c = *(const float4*)(Sr + i * 8 + 4);
        ushort4 u0 = *(const ushort4*)(upv + i * 8);
        ushort4 u1 = *(const ushort4*)(upv + i * 8 + 4);
        ushort4 r0, r1;
        r0.x = f2b(a.x * b2f(u0.x)); r0.y = f2b(a.y * b2f(u0.y));
        r0.z = f2b(a.z * b2f(u0.z)); r0.w = f2b(a.w * b2f(u0.w));
        r1.x = f2b(c.x * b2f(u1.x)); r1.y = f2b(c.y * b2f(u1.y));
        r1.z = f2b(c.z * b2f(u1.z)); r1.w = f2b(c.w * b2f(u1.w));
        *(ushort4*)(opv + i * 8) = r0;
        *(ushort4*)(opv + i * 8 + 4) = r1;
    }
}

// ------ rmsnorm + t_emb bias (entry): h += emb; y = norm(h) -----------------
__global__ void rmsnorm_bias(float* __restrict__ x, const float* __restrict__ t_emb,
                             const int* __restrict__ t_idx, const float* __restrict__ w,
                             unsigned short* __restrict__ y) {
    int r = blockIdx.x * 4 + (threadIdx.x >> 6);
    int lane = threadIdx.x & 63;
    const float* e = t_emb + (size_t)t_idx[r >> 8] * Hdim;
    float* xr = x + (size_t)r * Hdim;
    float4 a = *(const float4*)&xr[lane * 4];
    float4 b = *(const float4*)&xr[lane * 4 + 256];
    float4 c = *(const float4*)&xr[lane * 4 + 512];
    float4 ea = *(const float4*)&e[lane * 4];
    float4 eb = *(const float4*)&e[lane * 4 + 256];
    float4 ec = *(const float4*)&e[lane * 4 + 512];
    a.x += ea.x; a.y += ea.y; a.z += ea.z; a.w += ea.w;
    b.x += eb.x; b.y += eb.y; b.z += eb.z; b.w += eb.w;
    c.x += ec.x; c.y += ec.y; c.z += ec.z; c.w += ec.w;
    *(float4*)&xr[lane * 4]       = a;
    *(float4*)&xr[lane * 4 + 256] = b;
    *(float4*)&xr[lane * 4 + 512] = c;
    float ss = a.x * a.x + a.y * a.y + a.z * a.z + a.w * a.w
             + b.x * b.x + b.y * b.y + b.z * b.z + b.w * b.w
             + c.x * c.x + c.y * c.y + c.z * c.z + c.w * c.w;
#pragma unroll
    for (int o = 1; o < 64; o <<= 1) ss += __shfl_xor(ss, o, 64);
    float s = 1.0f / (sqrtf(ss / (float)Hdim) + 1e-6f);
    float4 wa = *(const float4*)&w[lane * 4];
    float4 wb = *(const float4*)&w[lane * 4 + 256];
    float4 wc = *(const float4*)&w[lane * 4 + 512];
    unsigned short* yr = y + (size_t)r * Hdim;
    ushort4 o0, o1, o2;
    o0.x = f2b(a.x * s * wa.x); o0.y = f2b(a.y * s * wa.y);
    o0.z = f2b(a.z * s * wa.z); o0.w = f2b(a.w * s * wa.w);
    o1.x = f2b(b.x * s * wb.x); o1.y = f2b(b.y * s * wb.y);
    o1.z = f2b(b.z * s * wb.z); o1.w = f2b(b.w * s * wb.w);
    o2.x = f2b(c.x * s * wc.x); o2.y = f2b(c.y * s * wc.y);
    o2.z = f2b(c.z * s * wc.z); o2.w = f2b(c.w * s * wc.w);
    *(ushort4*)&yr[lane * 4]       = o0;
    *(ushort4*)&yr[lane * 4 + 256] = o1;
    *(ushort4*)&yr[lane * 4 + 512] = o2;
}

// ------ rmsnorm with bf16 split-K partial fold (2 slices) --------------------
__global__ void rmsnorm_acc(float* __restrict__ x, const unsigned short* __restrict__ p,
                            const float* __restrict__ w, unsigned short* __restrict__ y) {
    int r = blockIdx.x * 4 + (threadIdx.x >> 6);
    int lane = threadIdx.x & 63;
    float* xr = x + (size_t)r * Hdim;
    float4 a = *(const float4*)&xr[lane * 4];
    float4 b = *(const float4*)&xr[lane * 4 + 256];
    float4 c = *(const float4*)&xr[lane * 4 + 512];
#pragma unroll
    for (int s = 0; s < 2; ++s) {
        const unsigned short* ps = p + (size_t)(s * Mrows + r) * Hdim;
        ushort4 a0 = *(const ushort4*)&ps[lane * 4];
        ushort4 b0 = *(const ushort4*)&ps[lane * 4 + 256];
        ushort4 c0 = *(const ushort4*)&ps[lane * 4 + 512];
        a.x += b2f(a0.x); a.y += b2f(a0.y); a.z += b2f(a0.z); a.w += b2f(a0.w);
        b.x += b2f(b0.x); b.y += b2f(b0.y); b.z += b2f(b0.z); b.w += b2f(b0.w);
        c.x += b2f(c0.x); c.y += b2f(c0.y); c.z += b2f(c0.z); c.w += b2f(c0.w);
    }
    *(float4*)&xr[lane * 4]       = a;
    *(float4*)&xr[lane * 4 + 256] = b;
    *(float4*)&xr[lane * 4 + 512] = c;
    float ss = a.x * a.x + a.y * a.y + a.z * a.z + a.w * a.w
             + b.x * b.x + b.y * b.y + b.z * b.z + b.w * b.w
             + c.x * c.x + c.y * c.y + c.z * c.z + c.w * c.w;
#pragma unroll
    for (int o = 1; o < 64; o <<= 1) ss += __shfl_xor(ss, o, 64);
    float s = 1.0f / (sqrtf(ss / (float)Hdim) + 1e-6f);
    float4 wa = *(const float4*)&w[lane * 4];
    float4 wb = *(const float4*)&w[lane * 4 + 256];
    float4 wc = *(const float4*)&w[lane * 4 + 512];
    unsigned short* yr = y + (size_t)r * Hdim;
    ushort4 o0, o1, o2;
    o0.x = f2b(a.x * s * wa.x); o0.y = f2b(a.y * s * wa.y);
    o0.z = f2b(a.z * s * wa.z); o0.w = f2b(a.w * s * wa.w);
    o1.x = f2b(b.x * s * wb.x); o1.y = f2b(b.y * s * wb.y);
    o1.z = f2b(b.z * s * wb.z); o1.w = f2b(b.w * s * wb.w);
    o2.x = f2b(c.x * s * wc.x); o2.y = f2b(c.y * s * wc.y);
    o2.z = f2b(c.z * s * wc.z); o2.w = f2b(c.w * s * wc.w);
    *(ushort4*)&yr[lane * 4]       = o0;
    *(ushort4*)&yr[lane * 4 + 256] = o1;
    *(ushort4*)&yr[lane * 4 + 512] = o2;
}

// ---------------- unpatchify ----------------
__global__ void unpatch_kernel(const float* __restrict__ y, float* __restrict__ out) {
    int bc = blockIdx.x;
    int iy = bc & 127;
    int t  = bc >> 7;
    int c  = t % 3;
    int b  = t / 3;
    int ix = threadIdx.x;
    int gy = iy >> 3, py = iy & 7, gx = ix >> 3, px = ix & 7;
    out[((size_t)(b * 3 + c) * IMG + iy) * IMG + ix] =
        y[(size_t)(b * Ltok + gy * 16 + gx) * PDim + (py * 8 + px) * 3 + c];
}

extern "C" void kernel_launch(void* const* d_in, const int* in_sizes, int n_in,
                              void* d_out, int out_size, void* d_ws, size_t ws_size,
                              hipStream_t stream) {
    const float* x        = (const float*)d_in[0];
    const int*   t_idx    = (const int*)  d_in[1];
    const float* patch_W  = (const float*)d_in[2];
    const float* t_emb    = (const float*)d_in[3];
    const float* Wuv      = (const float*)d_in[4];
    const float* Wout     = (const float*)d_in[5];
    const float* gnorm    = (const float*)d_in[6];
    const float* fnorm    = (const float*)d_in[7];
    const float* unpatchW = (const float*)d_in[8];
    float* out = (float*)d_out;

    // ---- workspace layout ----
    char* wsb = (char*)d_ws;
    size_t off = 0;
    auto alloc = [&](size_t bytes) { char* p = wsb + off; off += (bytes + 255) & ~(size_t)255; return p; };
    float* pe   = (float*)alloc(256 * 128 * 4);
    float* h    = (float*)alloc((size_t)Mrows * Hdim * 4);
    float* y    = (float*)alloc((size_t)Mrows * PDim * 4);
    unsigned short* pbuf = (unsigned short*)alloc((size_t)2 * Mrows * Hdim * 2);
    unsigned short* xp   = (unsigned short*)alloc((size_t)Mrows * PDim * 2);
    unsigned short* xn   = (unsigned short*)alloc((size_t)Mrows * Hdim * 2);
    unsigned short* u_bf = (unsigned short*)alloc((size_t)Mrows * Edim * 2);
    unsigned short* vT   = (unsigned short*)alloc((size_t)Bsz * Edim * Ltok * 2);
    unsigned short* qh   = (unsigned short*)alloc((size_t)Mrows * 128 * 2);
    unsigned short* kh   = (unsigned short*)alloc((size_t)Mrows * 128 * 2);
    unsigned short* o_bf = (unsigned short*)alloc((size_t)Mrows * Edim * 2);
    unsigned short* WuvT  = (unsigned short*)alloc((size_t)NLAY * UVW * Hdim * 2);
    unsigned short* WoutT = (unsigned short*)alloc((size_t)NLAY * Hdim * Edim * 2);
    unsigned short* patchWT   = (unsigned short*)alloc((size_t)Hdim * PDim * 2);
    unsigned short* unpatchWT = (unsigned short*)alloc((size_t)PDim * Hdim * 2);
    if (off > ws_size) return;   // distinct failure signature (out stays 0)

    pe_kernel<<<256, 128, 0, stream>>>(pe);
    patchify_kernel<<<Bsz * 3 * IMG, IMG, 0, stream>>>(x, xp);

    // weight transposes upfront (batched over layers)
    trans_kernel<<<dim3(Hdim / 32, PDim / 32, 1), dim3(32, 8), 0, stream>>>(
        patch_W, Hdim, 0, patchWT, PDim, 0);
    trans_kernel<<<dim3(PDim / 32, Hdim / 32, 1), dim3(32, 8), 0, stream>>>(
        unpatchW, PDim, 0, unpatchWT, Hdim, 0);
    trans_kernel<<<dim3(UVW / 32, Hdim / 32, NLAY), dim3(32, 8), 0, stream>>>(
        Wuv, UVW, (long long)Hdim * UVW, WuvT, Hdim, (long long)UVW * Hdim);
    trans_kernel<<<dim3(Hdim / 32, Edim / 32, NLAY), dim3(32, 8), 0, stream>>>(
        Wout, Hdim, (long long)Edim * Hdim, WoutT, Edim, (long long)Hdim * Edim);

    gemm_bf16<0><<<(Hdim / 128) * (Mrows / 128), 256, 0, stream>>>(
        xp, PDim, patchWT, PDim, h, Hdim, PDim, Hdim, Hdim / 128);

    rmsnorm_bias<<<Mrows / 4, 256, 0, stream>>>(h, t_emb, t_idx, gnorm, xn);
    for (int l = 0; l < NLAY; ++l) {
        gemm_uvqk8<<<13 * (Mrows / 256), 512, 0, stream>>>(
            xn, WuvT + (size_t)l * UVW * Hdim, u_bf, vT, qh, kh, pe);
        fused_attn<<<dim3(8, 4, Bsz), 256, 0, stream>>>(qh, kh, vT, u_bf, o_bf);
        gemm_wout<<<384, 256, 0, stream>>>(
            o_bf, WoutT + (size_t)l * Hdim * Edim, pbuf);
        const float* nw = (l + 1 < NLAY) ? gnorm + (size_t)(l + 1) * Hdim : fnorm;
        rmsnorm_acc<<<Mrows / 4, 256, 0, stream>>>(h, pbuf, nw, xn);
    }

    gemm_bf16<0><<<2 * (Mrows / 128), 256, 0, stream>>>(
        xn, Hdim, unpatchWT, Hdim, y, PDim, Hdim, PDim, 2);
    unpatch_kernel<<<Bsz * 3 * IMG, IMG, 0, stream>>>(y, out);
}

// Round 13
// 2726.712 us; speedup vs baseline: 1.0006x; 1.0006x over previous
//
#include <hip/hip_runtime.h>
#include <math.h>

#define IMG   128
#define Hdim  768
#define Edim  1536
#define Ltok  256
#define PDim  192
#define NLAY  24
#define Bsz   16
#define Mrows 4096          // B * L
#define UVW   3328          // 2E + 2K

typedef __bf16 bf16x8 __attribute__((ext_vector_type(8)));
typedef float  f32x4  __attribute__((ext_vector_type(4)));

__device__ __forceinline__ unsigned short f2b(float f) {
    unsigned int u = __float_as_uint(f);
    unsigned int r = (u + 0x7FFF + ((u >> 16) & 1)) >> 16;
    return (unsigned short)r;
}
__device__ __forceinline__ float b2f(unsigned short s) {
    return __uint_as_float((unsigned int)s << 16);
}
__device__ __forceinline__ unsigned int pk2(float lo, float hi) {
    return (unsigned int)f2b(lo) | ((unsigned int)f2b(hi) << 16);
}
__device__ __forceinline__ float silu(float x) {
    return x / (1.0f + expf(-x));
}
__device__ __forceinline__ void gload16(const void* g, void* l) {
    __builtin_amdgcn_global_load_lds(
        (const __attribute__((address_space(1))) void*)g,
        (__attribute__((address_space(3))) void*)l, 16, 0, 0);
}
// bijective XCD-chunking remap (m204)
__device__ __forceinline__ int xcd_wg() {
    int nwg = gridDim.x;
    int orig = blockIdx.x;
    int q8 = nwg >> 3, r8 = nwg & 7;
    int xcd = orig & 7, loc = orig >> 3;
    return (xcd < r8 ? xcd * (q8 + 1) : r8 * (q8 + 1) + (xcd - r8) * q8) + loc;
}

// ---------------- RoPE table ----------------
__global__ void pe_kernel(float* __restrict__ pe) {
    int l = blockIdx.x;
    int j = threadIdx.x;
    const float c = -logf(1000.0f) / 31.0f;
    int   sub = j & 31;
    float f   = expf(c * (float)sub);
    float pos = (j < 64) ? (float)(l >> 4) : (float)(l & 15);
    float ang = pos * f;
    pe[l * 128 + j] = ((j & 32) == 0) ? sinf(ang) : cosf(ang);
}

// ---------------- patchify -> bf16 ----------------
__global__ void patchify_kernel(const float* __restrict__ x, unsigned short* __restrict__ xp) {
    int bc = blockIdx.x;
    int iy = bc & 127;
    int t  = bc >> 7;
    int c  = t % 3;
    int b  = t / 3;
    int ix = threadIdx.x;
    float v = x[((size_t)(b * 3 + c) * IMG + iy) * IMG + ix];
    int gy = iy >> 3, py = iy & 7, gx = ix >> 3, px = ix & 7;
    xp[(size_t)(b * Ltok + gy * 16 + gx) * PDim + (py * 8 + px) * 3 + c] = f2b(v);
}

// ---------------- fp32 [R][C] -> bf16 transposed [C][R] ----------------
__global__ void trans_kernel(const float* __restrict__ src, int ldS, long long sS,
                             unsigned short* __restrict__ dst, int ldD, long long sD) {
    src += (long long)blockIdx.z * sS;
    dst += (long long)blockIdx.z * sD;
    __shared__ float t[32][33];
    int c0 = blockIdx.x * 32, r0 = blockIdx.y * 32;
    int tx = threadIdx.x, ty = threadIdx.y;   // (32,8)
#pragma unroll
    for (int i = 0; i < 4; ++i)
        t[ty + 8 * i][tx] = src[(size_t)(r0 + ty + 8 * i) * ldS + c0 + tx];
    __syncthreads();
#pragma unroll
    for (int i = 0; i < 4; ++i)
        dst[(size_t)(c0 + ty + 8 * i) * ldD + r0 + tx] = f2b(t[tx][ty + 8 * i]);
}

// ================= generic bf16 MFMA GEMM, double-buffered, XCD-swizzled ====
template <int ACC>
__launch_bounds__(256)
__global__ void gemm_bf16(const unsigned short* __restrict__ A, int lda,
                          const unsigned short* __restrict__ Bt, int ldb,
                          float* __restrict__ C, int ldc,
                          int Kt, int Nt, int nbx) {
    __shared__ unsigned short lsA[2][4096];
    __shared__ unsigned short lsB[2][4096];
    int wg = xcd_wg();
    int bx = wg % nbx, by = wg / nbx;
    int tid  = threadIdx.x;
    int lane = tid & 63, w = tid >> 6, wr = w >> 1, wc = w & 1;
    int row0 = by * 128, col0 = bx * 128;
    int fr = lane & 15, fk = (lane >> 4) * 8;
    f32x4 acc[4][4] = {};

    int c0 = tid, c1 = tid + 256;
    int ar0 = row0 + (c0 >> 2), ar1 = row0 + (c1 >> 2);
    int bn0 = col0 + (c0 >> 2), bn1 = col0 + (c1 >> 2);
    if (bn0 > Nt - 1) bn0 = Nt - 1;
    if (bn1 > Nt - 1) bn1 = Nt - 1;
    int ka0 = (c0 & 3) * 8, ka1 = (c1 & 3) * 8;

#define STAGE_G(buf, k0)                                                       \
    gload16(A  + (size_t)ar0 * lda + (k0) + ka0, &lsA[buf][c0 * 8]);           \
    gload16(A  + (size_t)ar1 * lda + (k0) + ka1, &lsA[buf][c1 * 8]);           \
    gload16(Bt + (size_t)bn0 * ldb + (k0) + ka0, &lsB[buf][c0 * 8]);           \
    gload16(Bt + (size_t)bn1 * ldb + (k0) + ka1, &lsB[buf][c1 * 8]);

    STAGE_G(0, 0);
    __syncthreads();
    int nt = Kt >> 5, cur = 0;
    for (int t = 0; t < nt; ++t) {
        if (t + 1 < nt) { STAGE_G(cur ^ 1, (t + 1) * 32); }
        bf16x8 af[4], bfr[4];
#pragma unroll
        for (int m = 0; m < 4; ++m)
            af[m] = *(const bf16x8*)(&lsA[cur][(wr * 64 + m * 16 + fr) * 32 + fk]);
#pragma unroll
        for (int n = 0; n < 4; ++n)
            bfr[n] = *(const bf16x8*)(&lsB[cur][(wc * 64 + n * 16 + fr) * 32 + fk]);
#pragma unroll
        for (int m = 0; m < 4; ++m)
#pragma unroll
            for (int n = 0; n < 4; ++n)
                acc[m][n] = __builtin_amdgcn_mfma_f32_16x16x32_bf16(af[m], bfr[n], acc[m][n], 0, 0, 0);
        __syncthreads();
        cur ^= 1;
    }
#undef STAGE_G

    int crow = (lane >> 4) * 4;
#pragma unroll
    for (int m = 0; m < 4; ++m) {
#pragma unroll
        for (int n = 0; n < 4; ++n) {
            int gc = col0 + wc * 64 + n * 16 + fr;
            if (gc >= Nt) continue;
#pragma unroll
            for (int j = 0; j < 4; ++j) {
                size_t idx = (size_t)(row0 + wr * 64 + m * 16 + crow + j) * ldc + gc;
                if (ACC) C[idx] += acc[m][n][j];
                else     C[idx]  = acc[m][n][j];
            }
        }
    }
}

// ================= wout GEMM, split-K=2, bf16 partials, coalesced stores =====
// A = o_bf [4096][1536], Bt = WoutT_l [768][1536]. grid 384: sk|by|bx.
__launch_bounds__(256)
__global__ void gemm_wout(const unsigned short* __restrict__ A,
                          const unsigned short* __restrict__ Bt,
                          unsigned short* __restrict__ P) {
    __shared__ char smw[32768];
    unsigned short (*lsA)[4096] = (unsigned short (*)[4096])smw;
    unsigned short (*lsB)[4096] = (unsigned short (*)[4096])(smw + 16384);
    int wg = xcd_wg();
    int sk = wg / 192, rem = wg % 192;
    int bx = rem % 6, by = rem / 6;
    int koff = sk * 768;
    unsigned short* C = P + (size_t)sk * Mrows * Hdim;
    int tid  = threadIdx.x;
    int lane = tid & 63, w = tid >> 6, wr = w >> 1, wc = w & 1;
    int row0 = by * 128, col0 = bx * 128;
    int fr = lane & 15, fk = (lane >> 4) * 8;
    f32x4 acc[4][4] = {};

    int c0 = tid, c1 = tid + 256;
    int ar0 = row0 + (c0 >> 2), ar1 = row0 + (c1 >> 2);
    int bn0 = col0 + (c0 >> 2), bn1 = col0 + (c1 >> 2);
    int ka0 = koff + (c0 & 3) * 8, ka1 = koff + (c1 & 3) * 8;

#define STAGE_W(buf, k0)                                                       \
    gload16(A  + (size_t)ar0 * Edim + (k0) + ka0, &lsA[buf][c0 * 8]);          \
    gload16(A  + (size_t)ar1 * Edim + (k0) + ka1, &lsA[buf][c1 * 8]);          \
    gload16(Bt + (size_t)bn0 * Edim + (k0) + ka0, &lsB[buf][c0 * 8]);          \
    gload16(Bt + (size_t)bn1 * Edim + (k0) + ka1, &lsB[buf][c1 * 8]);

    STAGE_W(0, 0);
    __syncthreads();
    int cur = 0;
    for (int t = 0; t < 24; ++t) {
        if (t + 1 < 24) { STAGE_W(cur ^ 1, (t + 1) * 32); }
        bf16x8 af[4], bfr[4];
#pragma unroll
        for (int m = 0; m < 4; ++m)
            af[m] = *(const bf16x8*)(&lsA[cur][(wr * 64 + m * 16 + fr) * 32 + fk]);
#pragma unroll
        for (int n = 0; n < 4; ++n)
            bfr[n] = *(const bf16x8*)(&lsB[cur][(wc * 64 + n * 16 + fr) * 32 + fk]);
#pragma unroll
        for (int m = 0; m < 4; ++m)
#pragma unroll
            for (int n = 0; n < 4; ++n)
                acc[m][n] = __builtin_amdgcn_mfma_f32_16x16x32_bf16(af[m], bfr[n], acc[m][n], 0, 0, 0);
        __syncthreads();
        cur ^= 1;
    }
#undef STAGE_W

    // ---- stage bf16 tile [m_l 128][n_l 128] in LDS, then 256B-row stores ----
    int crow = (lane >> 4) * 4;
    __syncthreads();
#pragma unroll
    for (int m = 0; m < 4; ++m) {
#pragma unroll
        for (int n = 0; n < 4; ++n) {
            int n_l = wc * 64 + n * 16 + fr;
#pragma unroll
            for (int j = 0; j < 4; ++j) {
                int m_l = wr * 64 + m * 16 + crow + j;
                int byte = (m_l * 256 + n_l * 2) ^ ((m_l & 7) << 4);
                *(unsigned short*)(smw + byte) = f2b(acc[m][n][j]);
            }
        }
    }
    __syncthreads();
    int grp = tid >> 4, l16 = tid & 15;
#pragma unroll
    for (int it = 0; it < 8; ++it) {
        int r = it * 16 + grp;
        int byte = (r * 256 + l16 * 16) ^ ((r & 7) << 4);
        int4 v = *(const int4*)(smw + byte);
        *(int4*)(C + (size_t)(row0 + r) * Hdim + col0 + l16 * 8) = v;
    }
}

// ================= uvqk GEMM: 256x256 tile, 8-phase counted-vmcnt pipeline ===
// A = xn [4096][768], Bt = WuvT_l [3328][768]. Grid 208 = 13 bx * 16 by, 512 thr.
// col-tiles 0-5: silu -> u_bf [m][e] (row-major); 6-11: silu -> vT [e][l];
// 12: rope -> qh/kh. All epilogues LDS-coalesced.
__global__ __launch_bounds__(512, 2)
void gemm_uvqk8(const unsigned short* __restrict__ A,
                const unsigned short* __restrict__ Bt,
                unsigned short* __restrict__ u_bf,
                unsigned short* __restrict__ vT,
                unsigned short* __restrict__ qh,
                unsigned short* __restrict__ kh,
                const float* __restrict__ pe) {
    __shared__ char smem[131072];   // 2 bufs * (A 2x16KB + B 2x16KB)
    int wg = xcd_wg();
    int bx = wg % 13, by = wg / 13;
    int tid = threadIdx.x, lane = tid & 63, wid = tid >> 6;
    int wm = wid >> 2, wn = wid & 3;            // 2 x 4 wave grid
    int row0 = by * 256, col0 = bx * 256;
    int fr = lane & 15, hi = lane >> 4;
    f32x4 acc[8][4] = {};

    // ---- staging: linear LDS dest, pre-swizzled global source ----
    int d0 = tid * 16, d1 = d0 + 8192;
    int s0 = d0 ^ (((d0 >> 7) & 7) << 4);
    int s1 = d1 ^ (((d1 >> 7) & 7) << 4);
    int sr0 = s0 >> 7, sc0 = (s0 & 127) >> 1;
    int sr1 = s1 >> 7, sc1 = (s1 & 127) >> 1;

#define STG_A(bufo, h, kt) do {                                                            \
    gload16(A + (size_t)(row0 + (h) * 128 + sr0) * Hdim + (kt) * 64 + sc0,                 \
            smem + (bufo) + (h) * 16384 + d0);                                             \
    gload16(A + (size_t)(row0 + (h) * 128 + sr1) * Hdim + (kt) * 64 + sc1,                 \
            smem + (bufo) + (h) * 16384 + d1); } while (0)
#define STG_B(bufo, h, kt) do {                                                            \
    gload16(Bt + (size_t)(col0 + (h) * 128 + sr0) * Hdim + (kt) * 64 + sc0,                \
            smem + (bufo) + 32768 + (h) * 16384 + d0);                                     \
    gload16(Bt + (size_t)(col0 + (h) * 128 + sr1) * Hdim + (kt) * 64 + sc1,                \
            smem + (bufo) + 32768 + (h) * 16384 + d1); } while (0)

    // ---- ds_read fragment addressing (swizzled) ----
    int axor = (fr & 7) << 4;
    int abase = wm * 16384 + fr * 128;
    int bbase = 32768 + (wn >> 1) * 16384 + ((wn & 1) * 64 + fr) * 128;
    int koff0 = (hi * 16) ^ axor;
    int koff1 = (hi * 16 + 64) ^ axor;

    // ---- prologue: kt0 (all 4 halves) + kt1 A-halves ----
    STG_A(0, 0, 0); STG_A(0, 1, 0); STG_B(0, 0, 0); STG_B(0, 1, 0);
    STG_A(65536, 0, 1); STG_A(65536, 1, 1);
    asm volatile("s_waitcnt vmcnt(4)" ::: "memory");
    __builtin_amdgcn_s_barrier();
    __builtin_amdgcn_sched_barrier(0);

    bf16x8 af[4][2], bf0[2][2], bf1[2][2];
    const int NKT = Hdim / 64;   // 12
    for (int kt = 0; kt < NKT; ++kt) {
        int curo = (kt & 1) << 16, nxto = curo ^ 65536;
        const char* bufc = smem + curo;

        // ---- phase 0: (mh0, nh0) ----
#pragma unroll
        for (int m = 0; m < 4; ++m) {
            af[m][0] = *(const bf16x8*)(bufc + abase + m * 2048 + koff0);
            af[m][1] = *(const bf16x8*)(bufc + abase + m * 2048 + koff1);
        }
#pragma unroll
        for (int n = 0; n < 2; ++n) {
            bf0[n][0] = *(const bf16x8*)(bufc + bbase + n * 2048 + koff0);
            bf0[n][1] = *(const bf16x8*)(bufc + bbase + n * 2048 + koff1);
        }
        if (kt + 1 < NKT) STG_B(nxto, 0, kt + 1);
        __builtin_amdgcn_s_setprio(1);
#pragma unroll
        for (int m = 0; m < 4; ++m)
#pragma unroll
            for (int n = 0; n < 2; ++n) {
                acc[m][n] = __builtin_amdgcn_mfma_f32_16x16x32_bf16(af[m][0], bf0[n][0], acc[m][n], 0, 0, 0);
                acc[m][n] = __builtin_amdgcn_mfma_f32_16x16x32_bf16(af[m][1], bf0[n][1], acc[m][n], 0, 0, 0);
            }
        __builtin_amdgcn_s_setprio(0);
        __builtin_amdgcn_s_barrier();
        __builtin_amdgcn_sched_barrier(0);

        // ---- phase 1: (mh0, nh1) ----
#pragma unroll
        for (int n = 0; n < 2; ++n) {
            bf1[n][0] = *(const bf16x8*)(bufc + bbase + (n + 2) * 2048 + koff0);
            bf1[n][1] = *(const bf16x8*)(bufc + bbase + (n + 2) * 2048 + koff1);
        }
        if (kt + 1 < NKT) STG_B(nxto, 1, kt + 1);
        __builtin_amdgcn_s_setprio(1);
#pragma unroll
        for (int m = 0; m < 4; ++m)
#pragma unroll
            for (int n = 0; n < 2; ++n) {
                acc[m][n + 2] = __builtin_amdgcn_mfma_f32_16x16x32_bf16(af[m][0], bf1[n][0], acc[m][n + 2], 0, 0, 0);
                acc[m][n + 2] = __builtin_amdgcn_mfma_f32_16x16x32_bf16(af[m][1], bf1[n][1], acc[m][n + 2], 0, 0, 0);
            }
        __builtin_amdgcn_s_setprio(0);
        __builtin_amdgcn_s_barrier();
        __builtin_amdgcn_sched_barrier(0);

        // ---- phase 2: (mh1, nh0) ----
#pragma unroll
        for (int m = 0; m < 4; ++m) {
            af[m][0] = *(const bf16x8*)(bufc + abase + (m + 4) * 2048 + koff0);
            af[m][1] = *(const bf16x8*)(bufc + abase + (m + 4) * 2048 + koff1);
        }
        __builtin_amdgcn_s_setprio(1);
#pragma unroll
        for (int m = 0; m < 4; ++m)
#pragma unroll
            for (int n = 0; n < 2; ++n) {
                acc[m + 4][n] = __builtin_amdgcn_mfma_f32_16x16x32_bf16(af[m][0], bf0[n][0], acc[m + 4][n], 0, 0, 0);
                acc[m + 4][n] = __builtin_amdgcn_mfma_f32_16x16x32_bf16(af[m][1], bf0[n][1], acc[m + 4][n], 0, 0, 0);
            }
        __builtin_amdgcn_s_setprio(0);
        __builtin_amdgcn_s_barrier();
        __builtin_amdgcn_sched_barrier(0);

        // ---- phase 3: (mh1, nh1) ----
        if (kt + 2 < NKT) { STG_A(curo, 0, kt + 2); STG_A(curo, 1, kt + 2); }
        __builtin_amdgcn_s_setprio(1);
#pragma unroll
        for (int m = 0; m < 4; ++m)
#pragma unroll
            for (int n = 0; n < 2; ++n) {
                acc[m + 4][n + 2] = __builtin_amdgcn_mfma_f32_16x16x32_bf16(af[m][0], bf1[n][0], acc[m + 4][n + 2], 0, 0, 0);
                acc[m + 4][n + 2] = __builtin_amdgcn_mfma_f32_16x16x32_bf16(af[m][1], bf1[n][1], acc[m + 4][n + 2], 0, 0, 0);
            }
        __builtin_amdgcn_s_setprio(0);
        asm volatile("s_waitcnt vmcnt(4)" ::: "memory");
        __builtin_amdgcn_s_barrier();
        __builtin_amdgcn_sched_barrier(0);
    }
#undef STG_A
#undef STG_B

    // ================= epilogue =================
    if (bx == 12) {
        // rope: 4 passes of 64 rows through LDS (fp32), q cols 0-127, k 128-255
        float* S = (float*)smem;
        const float qscale = 0.08838834764831845f;   // 128^-0.5
#pragma unroll
        for (int p = 0; p < 4; ++p) {
            __syncthreads();
            if (wm == (p >> 1)) {
#pragma unroll
                for (int m = 0; m < 4; ++m) {
                    int mf = (p & 1) * 4 + m;
                    int rl = m * 16 + hi * 4;
#pragma unroll
                    for (int n = 0; n < 4; ++n) {
                        int cl = wn * 64 + n * 16 + fr;
#pragma unroll
                        for (int j = 0; j < 4; ++j)
                            S[(rl + j) * 256 + cl] = acc[mf][n][j];
                    }
                }
            }
            __syncthreads();
            int r = tid >> 3;
            int dbase = (tid & 7) * 8;
            int row_g = row0 + p * 64 + r;
            int l = row_g & 255;
#pragma unroll
            for (int i = 0; i < 8; ++i) {
                int d = dbase + i;
                float sn = pe[l * 128 + d], cs = pe[l * 128 + 64 + d];
                float q1 = S[r * 256 + d],       q2 = S[r * 256 + d + 64];
                float k1 = S[r * 256 + d + 128], k2 = S[r * 256 + d + 192];
                qh[(size_t)row_g * 128 + d]      = f2b((q1 * cs - q2 * sn) * qscale);
                qh[(size_t)row_g * 128 + d + 64] = f2b((q2 * cs + q1 * sn) * qscale);
                kh[(size_t)row_g * 128 + d]      = f2b(k1 * cs - k2 * sn);
                kh[(size_t)row_g * 128 + d + 64] = f2b(k2 * cs + k1 * sn);
            }
        }
        return;
    }

    __syncthreads();
    if (bx < 6) {
        // ---- u: stage bf16 [m_l 256][e_l 256] (512B rows), coalesced row stores ----
#pragma unroll
        for (int mf = 0; mf < 8; ++mf) {
            int m0 = wm * 128 + mf * 16 + hi * 4;
#pragma unroll
            for (int nf = 0; nf < 4; ++nf) {
                int e_l = wn * 64 + nf * 16 + fr;
#pragma unroll
                for (int j = 0; j < 4; ++j) {
                    int m_l = m0 + j;
                    int byte = (m_l * 512 + e_l * 2) ^ ((m_l & 7) << 4);
                    *(unsigned short*)(smem + byte) = f2b(silu(acc[mf][nf][j]));
                }
            }
        }
        __syncthreads();
        int grp = tid >> 5, l32 = tid & 31;
#pragma unroll
        for (int it = 0; it < 16; ++it) {
            int r = it * 16 + grp;
            int byte = (r * 512 + l32 * 16) ^ ((r & 7) << 4);
            int4 v = *(const int4*)(smem + byte);
            *(int4*)(u_bf + (size_t)(row0 + r) * Edim + bx * 256 + l32 * 8) = v;
        }
        return;
    }

    // ---- v: stage bf16 [e_l 256][m_l 256] transpose, coalesced row stores ----
#pragma unroll
    for (int mf = 0; mf < 8; ++mf) {
        int m_l = wm * 128 + mf * 16 + hi * 4;
#pragma unroll
        for (int nf = 0; nf < 4; ++nf) {
            int e_l = wn * 64 + nf * 16 + fr;
            ushort4 pk;
            pk.x = f2b(silu(acc[mf][nf][0]));
            pk.y = f2b(silu(acc[mf][nf][1]));
            pk.z = f2b(silu(acc[mf][nf][2]));
            pk.w = f2b(silu(acc[mf][nf][3]));
            int byte = (e_l * 512 + m_l * 2) ^ ((e_l & 7) << 4);
            *(ushort4*)(smem + byte) = pk;
        }
    }
    __syncthreads();
    int er = tid >> 5, ch = (tid & 31) * 16;
#pragma unroll
    for (int it = 0; it < 16; ++it) {
        int e_l = it * 16 + er;
        int byte = (e_l * 512 + ch) ^ ((e_l & 7) << 4);
        int4 v = *(const int4*)(smem + byte);
        int e = col0 + e_l - Edim;
        unsigned short* dst = vT + ((size_t)(row0 >> 8) * Edim + e) * Ltok;
        *(int4*)((char*)dst + ch) = v;
    }
}

// ================= fused attention: softmax(q̂k̂ᵀ) @ V ⊙ u -> o_bf =================
// grid (ec=8, qt=4, b=16). O staged fp32 in LDS; u-mul + store coalesced.
__launch_bounds__(256)
__global__ void fused_attn(const unsigned short* __restrict__ qh,
                           const unsigned short* __restrict__ kh,
                           const unsigned short* __restrict__ vT,
                           const unsigned short* __restrict__ u_bf,
                           unsigned short* __restrict__ ob) {
    __shared__ float S[64 * 196];
    int ec = blockIdx.x, qt = blockIdx.y, b = blockIdx.z;
    int tid  = threadIdx.x;
    int lane = tid & 63, w = tid >> 6;
    int fr = lane & 15, hi = lane >> 4;
    int qbase = b * 256 + qt * 64 + w * 16;

    bf16x8 qf[4];
#pragma unroll
    for (int ks = 0; ks < 4; ++ks)
        qf[ks] = *(const bf16x8*)(qh + (size_t)(qbase + fr) * 128 + ks * 32 + hi * 8);
    f32x4 sacc[16] = {};
#pragma unroll
    for (int mf = 0; mf < 16; ++mf) {
#pragma unroll
        for (int ks = 0; ks < 4; ++ks) {
            bf16x8 kf = *(const bf16x8*)(kh + (size_t)(b * 256 + mf * 16 + fr) * 128 + ks * 32 + hi * 8);
            sacc[mf] = __builtin_amdgcn_mfma_f32_16x16x32_bf16(kf, qf[ks], sacc[mf], 0, 0, 0);
        }
    }

    float mx = -3.4e38f;
#pragma unroll
    for (int mf = 0; mf < 16; ++mf)
#pragma unroll
        for (int j = 0; j < 4; ++j)
            mx = fmaxf(mx, sacc[mf][j]);
    mx = fmaxf(mx, __shfl_xor(mx, 16, 64));
    mx = fmaxf(mx, __shfl_xor(mx, 32, 64));
    float sum = 0.f;
#pragma unroll
    for (int mf = 0; mf < 16; ++mf)
#pragma unroll
        for (int j = 0; j < 4; ++j) {
            float e = expf(sacc[mf][j] - mx);
            sacc[mf][j] = e;
            sum += e;
        }
    sum += __shfl_xor(sum, 16, 64);
    sum += __shfl_xor(sum, 32, 64);
    float inv = 1.0f / sum;

    unsigned int dw[16][2];
#pragma unroll
    for (int mf = 0; mf < 16; ++mf) {
        dw[mf][0] = pk2(sacc[mf][0] * inv, sacc[mf][1] * inv);
        dw[mf][1] = pk2(sacc[mf][2] * inv, sacc[mf][3] * inv);
    }

    int sA = fr + 32 * (hi & 1);
    int sB = sA + 16;
    bool up = (hi >> 1) != 0;
    unsigned int pa[8][4];
#pragma unroll
    for (int ks = 0; ks < 8; ++ks) {
        unsigned int a00 = __shfl((int)dw[2 * ks][0],     sA, 64);
        unsigned int a01 = __shfl((int)dw[2 * ks + 1][0], sA, 64);
        unsigned int a10 = __shfl((int)dw[2 * ks][1],     sA, 64);
        unsigned int a11 = __shfl((int)dw[2 * ks + 1][1], sA, 64);
        unsigned int b00 = __shfl((int)dw[2 * ks][0],     sB, 64);
        unsigned int b01 = __shfl((int)dw[2 * ks + 1][0], sB, 64);
        unsigned int b10 = __shfl((int)dw[2 * ks][1],     sB, 64);
        unsigned int b11 = __shfl((int)dw[2 * ks + 1][1], sB, 64);
        pa[ks][0] = up ? a01 : a00;
        pa[ks][1] = up ? a11 : a10;
        pa[ks][2] = up ? b01 : b00;
        pa[ks][3] = up ? b11 : b10;
    }

    // ---- PV: stage O (fp32) into LDS ----
    const unsigned short* vb = vT + (size_t)b * Edim * Ltok;
    int e0 = ec * 192;
    int rb = w * 16 + hi * 4;
#pragma unroll 2
    for (int ef = 0; ef < 12; ++ef) {
        int e = e0 + ef * 16 + fr;
        f32x4 oacc = {};
#pragma unroll
        for (int ks = 0; ks < 8; ++ks) {
            bf16x8 vf = *(const bf16x8*)(vb + (size_t)e * Ltok + ks * 32 + hi * 8);
            oacc = __builtin_amdgcn_mfma_f32_16x16x32_bf16(*(const bf16x8*)&pa[ks], vf, oacc, 0, 0, 0);
        }
        int el = ef * 16 + fr;
        S[(rb + 0) * 196 + el] = oacc[0];
        S[(rb + 1) * 196 + el] = oacc[1];
        S[(rb + 2) * 196 + el] = oacc[2];
        S[(rb + 3) * 196 + el] = oacc[3];
    }
    __syncthreads();

    // ---- u-mul + coalesced store: thread = (row r, quarter q) ----
    int r = tid >> 2, q = tid & 3;
    size_t grow = (size_t)(b * 256 + qt * 64 + r);
    const unsigned short* upv = u_bf + grow * Edim + e0 + q * 48;
    unsigned short* opv = ob + grow * Edim + e0 + q * 48;
    const float* Sr = S + r * 196 + q * 48;
#pragma unroll
    for (int i = 0; i < 6; ++i) {
        float4 a = *(const float4*)(Sr + i * 8);
        float4 c = *(const float4*)(Sr + i * 8 + 4);
        ushort4 u0 = *(const ushort4*)(upv + i * 8);
        ushort4 u1 = *(const ushort4*)(upv + i * 8 + 4);
        ushort4 r0, r1;
        r0.x = f2b(a.x * b2f(u0.x)); r0.y = f2b(a.y * b2f(u0.y));
        r0.z = f2b(a.z * b2f(u0.z)); r0.w = f2b(a.w * b2f(u0.w));
        r1.x = f2b(c.x * b2f(u1.x)); r1.y = f2b(c.y * b2f(u1.y));
        r1.z = f2b(c.z * b2f(u1.z)); r1.w = f2b(c.w * b2f(u1.w));
        *(ushort4*)(opv + i * 8) = r0;
        *(ushort4*)(opv + i * 8 + 4) = r1;
    }
}

// ------ rmsnorm + t_emb bias (entry): h += emb; y = norm(h) -----------------
__global__ void rmsnorm_bias(float* __restrict__ x, const float* __restrict__ t_emb,
                             const int* __restrict__ t_idx, const float* __restrict__ w,
                             unsigned short* __restrict__ y) {
    int r = blockIdx.x * 4 + (threadIdx.x >> 6);
    int lane = threadIdx.x & 63;
    const float* e = t_emb + (size_t)t_idx[r >> 8] * Hdim;
    float* xr = x + (size_t)r * Hdim;
    float4 a = *(const float4*)&xr[lane * 4];
    float4 b = *(const float4*)&xr[lane * 4 + 256];
    float4 c = *(const float4*)&xr[lane * 4 + 512];
    float4 ea = *(const float4*)&e[lane * 4];
    float4 eb = *(const float4*)&e[lane * 4 + 256];
    float4 ec = *(const float4*)&e[lane * 4 + 512];
    a.x += ea.x; a.y += ea.y; a.z += ea.z; a.w += ea.w;
    b.x += eb.x; b.y += eb.y; b.z += eb.z; b.w += eb.w;
    c.x += ec.x; c.y += ec.y; c.z += ec.z; c.w += ec.w;
    *(float4*)&xr[lane * 4]       = a;
    *(float4*)&xr[lane * 4 + 256] = b;
    *(float4*)&xr[lane * 4 + 512] = c;
    float ss = a.x * a.x + a.y * a.y + a.z * a.z + a.w * a.w
             + b.x * b.x + b.y * b.y + b.z * b.z + b.w * b.w
             + c.x * c.x + c.y * c.y + c.z * c.z + c.w * c.w;
#pragma unroll
    for (int o = 1; o < 64; o <<= 1) ss += __shfl_xor(ss, o, 64);
    float s = 1.0f / (sqrtf(ss / (float)Hdim) + 1e-6f);
    float4 wa = *(const float4*)&w[lane * 4];
    float4 wb = *(const float4*)&w[lane * 4 + 256];
    float4 wc = *(const float4*)&w[lane * 4 + 512];
    unsigned short* yr = y + (size_t)r * Hdim;
    ushort4 o0, o1, o2;
    o0.x = f2b(a.x * s * wa.x); o0.y = f2b(a.y * s * wa.y);
    o0.z = f2b(a.z * s * wa.z); o0.w = f2b(a.w * s * wa.w);
    o1.x = f2b(b.x * s * wb.x); o1.y = f2b(b.y * s * wb.y);
    o1.z = f2b(b.z * s * wb.z); o1.w = f2b(b.w * s * wb.w);
    o2.x = f2b(c.x * s * wc.x); o2.y = f2b(c.y * s * wc.y);
    o2.z = f2b(c.z * s * wc.z); o2.w = f2b(c.w * s * wc.w);
    *(ushort4*)&yr[lane * 4]       = o0;
    *(ushort4*)&yr[lane * 4 + 256] = o1;
    *(ushort4*)&yr[lane * 4 + 512] = o2;
}

// ------ rmsnorm with bf16 split-K partial fold (2 slices) --------------------
__global__ void rmsnorm_acc(float* __restrict__ x, const unsigned short* __restrict__ p,
                            const float* __restrict__ w, unsigned short* __restrict__ y) {
    int r = blockIdx.x * 4 + (threadIdx.x >> 6);
    int lane = threadIdx.x & 63;
    float* xr = x + (size_t)r * Hdim;
    float4 a = *(const float4*)&xr[lane * 4];
    float4 b = *(const float4*)&xr[lane * 4 + 256];
    float4 c = *(const float4*)&xr[lane * 4 + 512];
#pragma unroll
    for (int s = 0; s < 2; ++s) {
        const unsigned short* ps = p + (size_t)(s * Mrows + r) * Hdim;
        ushort4 a0 = *(const ushort4*)&ps[lane * 4];
        ushort4 b0 = *(const ushort4*)&ps[lane * 4 + 256];
        ushort4 c0 = *(const ushort4*)&ps[lane * 4 + 512];
        a.x += b2f(a0.x); a.y += b2f(a0.y); a.z += b2f(a0.z); a.w += b2f(a0.w);
        b.x += b2f(b0.x); b.y += b2f(b0.y); b.z += b2f(b0.z); b.w += b2f(b0.w);
        c.x += b2f(c0.x); c.y += b2f(c0.y); c.z += b2f(c0.z); c.w += b2f(c0.w);
    }
    *(float4*)&xr[lane * 4]       = a;
    *(float4*)&xr[lane * 4 + 256] = b;
    *(float4*)&xr[lane * 4 + 512] = c;
    float ss = a.x * a.x + a.y * a.y + a.z * a.z + a.w * a.w
             + b.x * b.x + b.y * b.y + b.z * b.z + b.w * b.w
             + c.x * c.x + c.y * c.y + c.z * c.z + c.w * c.w;
#pragma unroll
    for (int o = 1; o < 64; o <<= 1) ss += __shfl_xor(ss, o, 64);
    float s = 1.0f / (sqrtf(ss / (float)Hdim) + 1e-6f);
    float4 wa = *(const float4*)&w[lane * 4];
    float4 wb = *(const float4*)&w[lane * 4 + 256];
    float4 wc = *(const float4*)&w[lane * 4 + 512];
    unsigned short* yr = y + (size_t)r * Hdim;
    ushort4 o0, o1, o2;
    o0.x = f2b(a.x * s * wa.x); o0.y = f2b(a.y * s * wa.y);
    o0.z = f2b(a.z * s * wa.z); o0.w = f2b(a.w * s * wa.w);
    o1.x = f2b(b.x * s * wb.x); o1.y = f2b(b.y * s * wb.y);
    o1.z = f2b(b.z * s * wb.z); o1.w = f2b(b.w * s * wb.w);
    o2.x = f2b(c.x * s * wc.x); o2.y = f2b(c.y * s * wc.y);
    o2.z = f2b(c.z * s * wc.z); o2.w = f2b(c.w * s * wc.w);
    *(ushort4*)&yr[lane * 4]       = o0;
    *(ushort4*)&yr[lane * 4 + 256] = o1;
    *(ushort4*)&yr[lane * 4 + 512] = o2;
}

// ---------------- unpatchify ----------------
__global__ void unpatch_kernel(const float* __restrict__ y, float* __restrict__ out) {
    int bc = blockIdx.x;
    int iy = bc & 127;
    int t  = bc >> 7;
    int c  = t % 3;
    int b  = t / 3;
    int ix = threadIdx.x;
    int gy = iy >> 3, py = iy & 7, gx = ix >> 3, px = ix & 7;
    out[((size_t)(b * 3 + c) * IMG + iy) * IMG + ix] =
        y[(size_t)(b * Ltok + gy * 16 + gx) * PDim + (py * 8 + px) * 3 + c];
}

extern "C" void kernel_launch(void* const* d_in, const int* in_sizes, int n_in,
                              void* d_out, int out_size, void* d_ws, size_t ws_size,
                              hipStream_t stream) {
    const float* x        = (const float*)d_in[0];
    const int*   t_idx    = (const int*)  d_in[1];
    const float* patch_W  = (const float*)d_in[2];
    const float* t_emb    = (const float*)d_in[3];
    const float* Wuv      = (const float*)d_in[4];
    const float* Wout     = (const float*)d_in[5];
    const float* gnorm    = (const float*)d_in[6];
    const float* fnorm    = (const float*)d_in[7];
    const float* unpatchW = (const float*)d_in[8];
    float* out = (float*)d_out;

    // ---- workspace layout ----
    char* wsb = (char*)d_ws;
    size_t off = 0;
    auto alloc = [&](size_t bytes) { char* p = wsb + off; off += (bytes + 255) & ~(size_t)255; return p; };
    float* pe   = (float*)alloc(256 * 128 * 4);
    float* h    = (float*)alloc((size_t)Mrows * Hdim * 4);
    float* y    = (float*)alloc((size_t)Mrows * PDim * 4);
    unsigned short* pbuf = (unsigned short*)alloc((size_t)2 * Mrows * Hdim * 2);
    unsigned short* xp   = (unsigned short*)alloc((size_t)Mrows * PDim * 2);
    unsigned short* xn   = (unsigned short*)alloc((size_t)Mrows * Hdim * 2);
    unsigned short* u_bf = (unsigned short*)alloc((size_t)Mrows * Edim * 2);
    unsigned short* vT   = (unsigned short*)alloc((size_t)Bsz * Edim * Ltok * 2);
    unsigned short* qh   = (unsigned short*)alloc((size_t)Mrows * 128 * 2);
    unsigned short* kh   = (unsigned short*)alloc((size_t)Mrows * 128 * 2);
    unsigned short* o_bf = (unsigned short*)alloc((size_t)Mrows * Edim * 2);
    unsigned short* WuvT  = (unsigned short*)alloc((size_t)NLAY * UVW * Hdim * 2);
    unsigned short* WoutT = (unsigned short*)alloc((size_t)NLAY * Hdim * Edim * 2);
    unsigned short* patchWT   = (unsigned short*)alloc((size_t)Hdim * PDim * 2);
    unsigned short* unpatchWT = (unsigned short*)alloc((size_t)PDim * Hdim * 2);
    if (off > ws_size) return;   // distinct failure signature (out stays 0)

    pe_kernel<<<256, 128, 0, stream>>>(pe);
    patchify_kernel<<<Bsz * 3 * IMG, IMG, 0, stream>>>(x, xp);

    // weight transposes upfront (batched over layers)
    trans_kernel<<<dim3(Hdim / 32, PDim / 32, 1), dim3(32, 8), 0, stream>>>(
        patch_W, Hdim, 0, patchWT, PDim, 0);
    trans_kernel<<<dim3(PDim / 32, Hdim / 32, 1), dim3(32, 8), 0, stream>>>(
        unpatchW, PDim, 0, unpatchWT, Hdim, 0);
    trans_kernel<<<dim3(UVW / 32, Hdim / 32, NLAY), dim3(32, 8), 0, stream>>>(
        Wuv, UVW, (long long)Hdim * UVW, WuvT, Hdim, (long long)UVW * Hdim);
    trans_kernel<<<dim3(Hdim / 32, Edim / 32, NLAY), dim3(32, 8), 0, stream>>>(
        Wout, Hdim, (long long)Edim * Hdim, WoutT, Edim, (long long)Hdim * Edim);

    gemm_bf16<0><<<(Hdim / 128) * (Mrows / 128), 256, 0, stream>>>(
        xp, PDim, patchWT, PDim, h, Hdim, PDim, Hdim, Hdim / 128);

    rmsnorm_bias<<<Mrows / 4, 256, 0, stream>>>(h, t_emb, t_idx, gnorm, xn);
    for (int l = 0; l < NLAY; ++l) {
        gemm_uvqk8<<<13 * (Mrows / 256), 512, 0, stream>>>(
            xn, WuvT + (size_t)l * UVW * Hdim, u_bf, vT, qh, kh, pe);
        fused_attn<<<dim3(8, 4, Bsz), 256, 0, stream>>>(qh, kh, vT, u_bf, o_bf);
        gemm_wout<<<384, 256, 0, stream>>>(
            o_bf, WoutT + (size_t)l * Hdim * Edim, pbuf);
        const float* nw = (l + 1 < NLAY) ? gnorm + (size_t)(l + 1) * Hdim : fnorm;
        rmsnorm_acc<<<Mrows / 4, 256, 0, stream>>>(h, pbuf, nw, xn);
    }

    gemm_bf16<0><<<2 * (Mrows / 128), 256, 0, stream>>>(
        xn, Hdim, unpatchWT, Hdim, y, PDim, Hdim, PDim, 2);
    unpatch_kernel<<<Bsz * 3 * IMG, IMG, 0, stream>>>(y, out);
}

// Round 15
// 2687.158 us; speedup vs baseline: 1.0154x; 1.0147x over previous
//
#include <hip/hip_runtime.h>
#include <math.h>

#define IMG   128
#define Hdim  768
#define Edim  1536
#define Ltok  256
#define PDim  192
#define NLAY  24
#define Bsz   16
#define Mrows 4096          // B * L
#define UVW   3328          // 2E + 2K

typedef __bf16 bf16x8 __attribute__((ext_vector_type(8)));
typedef float  f32x4  __attribute__((ext_vector_type(4)));

__device__ __forceinline__ unsigned short f2b(float f) {
    unsigned int u = __float_as_uint(f);
    unsigned int r = (u + 0x7FFF + ((u >> 16) & 1)) >> 16;
    return (unsigned short)r;
}
__device__ __forceinline__ float b2f(unsigned short s) {
    return __uint_as_float((unsigned int)s << 16);
}
__device__ __forceinline__ unsigned int pk2(float lo, float hi) {
    return (unsigned int)f2b(lo) | ((unsigned int)f2b(hi) << 16);
}
__device__ __forceinline__ float silu(float x) {
    return x / (1.0f + expf(-x));
}
__device__ __forceinline__ void gload16(const void* g, void* l) {
    __builtin_amdgcn_global_load_lds(
        (const __attribute__((address_space(1))) void*)g,
        (__attribute__((address_space(3))) void*)l, 16, 0, 0);
}
// bijective XCD-chunking remap (m204)
__device__ __forceinline__ int xcd_wg() {
    int nwg = gridDim.x;
    int orig = blockIdx.x;
    int q8 = nwg >> 3, r8 = nwg & 7;
    int xcd = orig & 7, loc = orig >> 3;
    return (xcd < r8 ? xcd * (q8 + 1) : r8 * (q8 + 1) + (xcd - r8) * q8) + loc;
}

// ---------------- RoPE table ----------------
__global__ void pe_kernel(float* __restrict__ pe) {
    int l = blockIdx.x;
    int j = threadIdx.x;
    const float c = -logf(1000.0f) / 31.0f;
    int   sub = j & 31;
    float f   = expf(c * (float)sub);
    float pos = (j < 64) ? (float)(l >> 4) : (float)(l & 15);
    float ang = pos * f;
    pe[l * 128 + j] = ((j & 32) == 0) ? sinf(ang) : cosf(ang);
}

// ---------------- patchify -> bf16 ----------------
__global__ void patchify_kernel(const float* __restrict__ x, unsigned short* __restrict__ xp) {
    int bc = blockIdx.x;
    int iy = bc & 127;
    int t  = bc >> 7;
    int c  = t % 3;
    int b  = t / 3;
    int ix = threadIdx.x;
    float v = x[((size_t)(b * 3 + c) * IMG + iy) * IMG + ix];
    int gy = iy >> 3, py = iy & 7, gx = ix >> 3, px = ix & 7;
    xp[(size_t)(b * Ltok + gy * 16 + gx) * PDim + (py * 8 + px) * 3 + c] = f2b(v);
}

// ---------------- fp32 [R][C] -> bf16 transposed [C][R] ----------------
__global__ void trans_kernel(const float* __restrict__ src, int ldS, long long sS,
                             unsigned short* __restrict__ dst, int ldD, long long sD) {
    src += (long long)blockIdx.z * sS;
    dst += (long long)blockIdx.z * sD;
    __shared__ float t[32][33];
    int c0 = blockIdx.x * 32, r0 = blockIdx.y * 32;
    int tx = threadIdx.x, ty = threadIdx.y;   // (32,8)
#pragma unroll
    for (int i = 0; i < 4; ++i)
        t[ty + 8 * i][tx] = src[(size_t)(r0 + ty + 8 * i) * ldS + c0 + tx];
    __syncthreads();
#pragma unroll
    for (int i = 0; i < 4; ++i)
        dst[(size_t)(c0 + ty + 8 * i) * ldD + r0 + tx] = f2b(t[tx][ty + 8 * i]);
}

// ================= generic bf16 MFMA GEMM, double-buffered, XCD-swizzled ====
template <int ACC>
__launch_bounds__(256)
__global__ void gemm_bf16(const unsigned short* __restrict__ A, int lda,
                          const unsigned short* __restrict__ Bt, int ldb,
                          float* __restrict__ C, int ldc,
                          int Kt, int Nt, int nbx) {
    __shared__ unsigned short lsA[2][4096];
    __shared__ unsigned short lsB[2][4096];
    int wg = xcd_wg();
    int bx = wg % nbx, by = wg / nbx;
    int tid  = threadIdx.x;
    int lane = tid & 63, w = tid >> 6, wr = w >> 1, wc = w & 1;
    int row0 = by * 128, col0 = bx * 128;
    int fr = lane & 15, fk = (lane >> 4) * 8;
    f32x4 acc[4][4] = {};

    int c0 = tid, c1 = tid + 256;
    int ar0 = row0 + (c0 >> 2), ar1 = row0 + (c1 >> 2);
    int bn0 = col0 + (c0 >> 2), bn1 = col0 + (c1 >> 2);
    if (bn0 > Nt - 1) bn0 = Nt - 1;
    if (bn1 > Nt - 1) bn1 = Nt - 1;
    int ka0 = (c0 & 3) * 8, ka1 = (c1 & 3) * 8;

#define STAGE_G(buf, k0)                                                       \
    gload16(A  + (size_t)ar0 * lda + (k0) + ka0, &lsA[buf][c0 * 8]);           \
    gload16(A  + (size_t)ar1 * lda + (k0) + ka1, &lsA[buf][c1 * 8]);           \
    gload16(Bt + (size_t)bn0 * ldb + (k0) + ka0, &lsB[buf][c0 * 8]);           \
    gload16(Bt + (size_t)bn1 * ldb + (k0) + ka1, &lsB[buf][c1 * 8]);

    STAGE_G(0, 0);
    __syncthreads();
    int nt = Kt >> 5, cur = 0;
    for (int t = 0; t < nt; ++t) {
        if (t + 1 < nt) { STAGE_G(cur ^ 1, (t + 1) * 32); }
        bf16x8 af[4], bfr[4];
#pragma unroll
        for (int m = 0; m < 4; ++m)
            af[m] = *(const bf16x8*)(&lsA[cur][(wr * 64 + m * 16 + fr) * 32 + fk]);
#pragma unroll
        for (int n = 0; n < 4; ++n)
            bfr[n] = *(const bf16x8*)(&lsB[cur][(wc * 64 + n * 16 + fr) * 32 + fk]);
#pragma unroll
        for (int m = 0; m < 4; ++m)
#pragma unroll
            for (int n = 0; n < 4; ++n)
                acc[m][n] = __builtin_amdgcn_mfma_f32_16x16x32_bf16(af[m], bfr[n], acc[m][n], 0, 0, 0);
        __syncthreads();
        cur ^= 1;
    }
#undef STAGE_G

    int crow = (lane >> 4) * 4;
#pragma unroll
    for (int m = 0; m < 4; ++m) {
#pragma unroll
        for (int n = 0; n < 4; ++n) {
            int gc = col0 + wc * 64 + n * 16 + fr;
            if (gc >= Nt) continue;
#pragma unroll
            for (int j = 0; j < 4; ++j) {
                size_t idx = (size_t)(row0 + wr * 64 + m * 16 + crow + j) * ldc + gc;
                if (ACC) C[idx] += acc[m][n][j];
                else     C[idx]  = acc[m][n][j];
            }
        }
    }
}

// ================= wout GEMM, split-K=4, bf16 partials =======================
// A = o_bf [4096][1536], Bt = WoutT_l [768][1536]. grid 768: sk|by|bx.
// P[sk][4096][768] bf16 partials (residual add fused into next rmsnorm).
__launch_bounds__(256)
__global__ void gemm_wout(const unsigned short* __restrict__ A,
                          const unsigned short* __restrict__ Bt,
                          unsigned short* __restrict__ P) {
    __shared__ unsigned short lsA[2][4096];
    __shared__ unsigned short lsB[2][4096];
    int wg = xcd_wg();
    int sk = wg / 192, rem = wg % 192;
    int bx = rem % 6, by = rem / 6;
    int koff = sk * 384;
    unsigned short* C = P + (size_t)sk * Mrows * Hdim;
    int tid  = threadIdx.x;
    int lane = tid & 63, w = tid >> 6, wr = w >> 1, wc = w & 1;
    int row0 = by * 128, col0 = bx * 128;
    int fr = lane & 15, fk = (lane >> 4) * 8;
    f32x4 acc[4][4] = {};

    int c0 = tid, c1 = tid + 256;
    int ar0 = row0 + (c0 >> 2), ar1 = row0 + (c1 >> 2);
    int bn0 = col0 + (c0 >> 2), bn1 = col0 + (c1 >> 2);
    int ka0 = koff + (c0 & 3) * 8, ka1 = koff + (c1 & 3) * 8;

#define STAGE_W(buf, k0)                                                       \
    gload16(A  + (size_t)ar0 * Edim + (k0) + ka0, &lsA[buf][c0 * 8]);          \
    gload16(A  + (size_t)ar1 * Edim + (k0) + ka1, &lsA[buf][c1 * 8]);          \
    gload16(Bt + (size_t)bn0 * Edim + (k0) + ka0, &lsB[buf][c0 * 8]);          \
    gload16(Bt + (size_t)bn1 * Edim + (k0) + ka1, &lsB[buf][c1 * 8]);

    STAGE_W(0, 0);
    __syncthreads();
    int cur = 0;
    for (int t = 0; t < 12; ++t) {
        if (t + 1 < 12) { STAGE_W(cur ^ 1, (t + 1) * 32); }
        bf16x8 af[4], bfr[4];
#pragma unroll
        for (int m = 0; m < 4; ++m)
            af[m] = *(const bf16x8*)(&lsA[cur][(wr * 64 + m * 16 + fr) * 32 + fk]);
#pragma unroll
        for (int n = 0; n < 4; ++n)
            bfr[n] = *(const bf16x8*)(&lsB[cur][(wc * 64 + n * 16 + fr) * 32 + fk]);
#pragma unroll
        for (int m = 0; m < 4; ++m)
#pragma unroll
            for (int n = 0; n < 4; ++n)
                acc[m][n] = __builtin_amdgcn_mfma_f32_16x16x32_bf16(af[m], bfr[n], acc[m][n], 0, 0, 0);
        __syncthreads();
        cur ^= 1;
    }
#undef STAGE_W

    int crow = (lane >> 4) * 4;
#pragma unroll
    for (int m = 0; m < 4; ++m) {
#pragma unroll
        for (int n = 0; n < 4; ++n) {
            int gc = col0 + wc * 64 + n * 16 + fr;
#pragma unroll
            for (int j = 0; j < 4; ++j)
                C[(size_t)(row0 + wr * 64 + m * 16 + crow + j) * Hdim + gc] = f2b(acc[m][n][j]);
        }
    }
}

// ================= uvqk GEMM: 256x256 tile, 8-phase counted-vmcnt pipeline ===
// A = xn [4096][768], Bt = WuvT_l [3328][768]. Grid 208 = 13 bx * 16 by, 512 thr.
// BK=64, 2-K-tile double buffer, T2 XOR-swizzle, T5 setprio.
// col-tiles 0-5: silu->uT; 6-11: silu->vT; 12: rope->qh/kh.
// TAIL FIX (R14 race): vmcnt(4) is only safe while A(kt+2) loads sit behind
// B(kt+1) in the queue; on the last two iterations A(kt+2) is not issued, so
// vmcnt(4) could leave B(kt+1) in flight across the barrier -> stale ds_reads.
// Drain to vmcnt(0) when kt+2 >= NKT.
__global__ __launch_bounds__(512, 2)
void gemm_uvqk8(const unsigned short* __restrict__ A,
                const unsigned short* __restrict__ Bt,
                unsigned short* __restrict__ uT,
                unsigned short* __restrict__ vT,
                unsigned short* __restrict__ qh,
                unsigned short* __restrict__ kh,
                const float* __restrict__ pe) {
    __shared__ char smem[131072];   // 2 bufs * (A 2x16KB + B 2x16KB)
    int wg = xcd_wg();
    int bx = wg % 13, by = wg / 13;
    int tid = threadIdx.x, lane = tid & 63, wid = tid >> 6;
    int wm = wid >> 2, wn = wid & 3;            // 2 x 4 wave grid
    int row0 = by * 256, col0 = bx * 256;
    int fr = lane & 15, hi = lane >> 4;
    f32x4 acc[8][4] = {};

    // ---- staging: linear LDS dest, pre-swizzled global source ----
    int d0 = tid * 16, d1 = d0 + 8192;
    int s0 = d0 ^ (((d0 >> 7) & 7) << 4);
    int s1 = d1 ^ (((d1 >> 7) & 7) << 4);
    int sr0 = s0 >> 7, sc0 = (s0 & 127) >> 1;
    int sr1 = s1 >> 7, sc1 = (s1 & 127) >> 1;

#define STG_A(bufo, h, kt) do {                                                            \
    gload16(A + (size_t)(row0 + (h) * 128 + sr0) * Hdim + (kt) * 64 + sc0,                 \
            smem + (bufo) + (h) * 16384 + d0);                                             \
    gload16(A + (size_t)(row0 + (h) * 128 + sr1) * Hdim + (kt) * 64 + sc1,                 \
            smem + (bufo) + (h) * 16384 + d1); } while (0)
#define STG_B(bufo, h, kt) do {                                                            \
    gload16(Bt + (size_t)(col0 + (h) * 128 + sr0) * Hdim + (kt) * 64 + sc0,                \
            smem + (bufo) + 32768 + (h) * 16384 + d0);                                     \
    gload16(Bt + (size_t)(col0 + (h) * 128 + sr1) * Hdim + (kt) * 64 + sc1,                \
            smem + (bufo) + 32768 + (h) * 16384 + d1); } while (0)

    // ---- ds_read fragment addressing (swizzled) ----
    int axor = (fr & 7) << 4;
    int abase = wm * 16384 + fr * 128;
    int bbase = 32768 + (wn >> 1) * 16384 + ((wn & 1) * 64 + fr) * 128;
    int koff0 = (hi * 16) ^ axor;
    int koff1 = (hi * 16 + 64) ^ axor;

    // ---- prologue: kt0 (all 4 halves) + kt1 A-halves ----
    STG_A(0, 0, 0); STG_A(0, 1, 0); STG_B(0, 0, 0); STG_B(0, 1, 0);
    STG_A(65536, 0, 1); STG_A(65536, 1, 1);
    asm volatile("s_waitcnt vmcnt(4)" ::: "memory");
    __builtin_amdgcn_s_barrier();
    __builtin_amdgcn_sched_barrier(0);

    bf16x8 af[4][2], bf0[2][2], bf1[2][2];
    const int NKT = Hdim / 64;   // 12
    for (int kt = 0; kt < NKT; ++kt) {
        int curo = (kt & 1) << 16, nxto = curo ^ 65536;
        const char* bufc = smem + curo;

        // ---- phase 0: (mh0, nh0) ----
#pragma unroll
        for (int m = 0; m < 4; ++m) {
            af[m][0] = *(const bf16x8*)(bufc + abase + m * 2048 + koff0);
            af[m][1] = *(const bf16x8*)(bufc + abase + m * 2048 + koff1);
        }
#pragma unroll
        for (int n = 0; n < 2; ++n) {
            bf0[n][0] = *(const bf16x8*)(bufc + bbase + n * 2048 + koff0);
            bf0[n][1] = *(const bf16x8*)(bufc + bbase + n * 2048 + koff1);
        }
        if (kt + 1 < NKT) STG_B(nxto, 0, kt + 1);
        __builtin_amdgcn_s_setprio(1);
#pragma unroll
        for (int m = 0; m < 4; ++m)
#pragma unroll
            for (int n = 0; n < 2; ++n) {
                acc[m][n] = __builtin_amdgcn_mfma_f32_16x16x32_bf16(af[m][0], bf0[n][0], acc[m][n], 0, 0, 0);
                acc[m][n] = __builtin_amdgcn_mfma_f32_16x16x32_bf16(af[m][1], bf0[n][1], acc[m][n], 0, 0, 0);
            }
        __builtin_amdgcn_s_setprio(0);
        __builtin_amdgcn_s_barrier();
        __builtin_amdgcn_sched_barrier(0);

        // ---- phase 1: (mh0, nh1) ----
#pragma unroll
        for (int n = 0; n < 2; ++n) {
            bf1[n][0] = *(const bf16x8*)(bufc + bbase + (n + 2) * 2048 + koff0);
            bf1[n][1] = *(const bf16x8*)(bufc + bbase + (n + 2) * 2048 + koff1);
        }
        if (kt + 1 < NKT) STG_B(nxto, 1, kt + 1);
        __builtin_amdgcn_s_setprio(1);
#pragma unroll
        for (int m = 0; m < 4; ++m)
#pragma unroll
            for (int n = 0; n < 2; ++n) {
                acc[m][n + 2] = __builtin_amdgcn_mfma_f32_16x16x32_bf16(af[m][0], bf1[n][0], acc[m][n + 2], 0, 0, 0);
                acc[m][n + 2] = __builtin_amdgcn_mfma_f32_16x16x32_bf16(af[m][1], bf1[n][1], acc[m][n + 2], 0, 0, 0);
            }
        __builtin_amdgcn_s_setprio(0);
        __builtin_amdgcn_s_barrier();
        __builtin_amdgcn_sched_barrier(0);

        // ---- phase 2: (mh1, nh0) ----
#pragma unroll
        for (int m = 0; m < 4; ++m) {
            af[m][0] = *(const bf16x8*)(bufc + abase + (m + 4) * 2048 + koff0);
            af[m][1] = *(const bf16x8*)(bufc + abase + (m + 4) * 2048 + koff1);
        }
        __builtin_amdgcn_s_setprio(1);
#pragma unroll
        for (int m = 0; m < 4; ++m)
#pragma unroll
            for (int n = 0; n < 2; ++n) {
                acc[m + 4][n] = __builtin_amdgcn_mfma_f32_16x16x32_bf16(af[m][0], bf0[n][0], acc[m + 4][n], 0, 0, 0);
                acc[m + 4][n] = __builtin_amdgcn_mfma_f32_16x16x32_bf16(af[m][1], bf0[n][1], acc[m + 4][n], 0, 0, 0);
            }
        __builtin_amdgcn_s_setprio(0);
        __builtin_amdgcn_s_barrier();
        __builtin_amdgcn_sched_barrier(0);

        // ---- phase 3: (mh1, nh1) ----
        if (kt + 2 < NKT) { STG_A(curo, 0, kt + 2); STG_A(curo, 1, kt + 2); }
        __builtin_amdgcn_s_setprio(1);
#pragma unroll
        for (int m = 0; m < 4; ++m)
#pragma unroll
            for (int n = 0; n < 2; ++n) {
                acc[m + 4][n + 2] = __builtin_amdgcn_mfma_f32_16x16x32_bf16(af[m][0], bf1[n][0], acc[m + 4][n + 2], 0, 0, 0);
                acc[m + 4][n + 2] = __builtin_amdgcn_mfma_f32_16x16x32_bf16(af[m][1], bf1[n][1], acc[m + 4][n + 2], 0, 0, 0);
            }
        __builtin_amdgcn_s_setprio(0);
        if (kt + 2 < NKT) {
            asm volatile("s_waitcnt vmcnt(4)" ::: "memory");
        } else {
            // tail: A(kt+2) not issued, so vmcnt(4) would leave B(kt+1) in
            // flight across the barrier (R14 failure). Full drain.
            asm volatile("s_waitcnt vmcnt(0)" ::: "memory");
        }
        __builtin_amdgcn_s_barrier();
        __builtin_amdgcn_sched_barrier(0);
    }
#undef STG_A
#undef STG_B

    // ================= epilogue =================
    if (bx == 12) {
        // rope: 4 passes of 64 rows through LDS (fp32), q cols 0-127, k 128-255
        float* S = (float*)smem;
        const float qscale = 0.08838834764831845f;   // 128^-0.5
#pragma unroll
        for (int p = 0; p < 4; ++p) {
            __syncthreads();
            if (wm == (p >> 1)) {
#pragma unroll
                for (int m = 0; m < 4; ++m) {
                    int mf = (p & 1) * 4 + m;
                    int rl = m * 16 + hi * 4;
#pragma unroll
                    for (int n = 0; n < 4; ++n) {
                        int cl = wn * 64 + n * 16 + fr;
#pragma unroll
                        for (int j = 0; j < 4; ++j)
                            S[(rl + j) * 256 + cl] = acc[mf][n][j];
                    }
                }
            }
            __syncthreads();
            int r = tid >> 3;
            int dbase = (tid & 7) * 8;
            int row_g = row0 + p * 64 + r;
            int l = row_g & 255;
#pragma unroll
            for (int i = 0; i < 8; ++i) {
                int d = dbase + i;
                float sn = pe[l * 128 + d], cs = pe[l * 128 + 64 + d];
                float q1 = S[r * 256 + d],       q2 = S[r * 256 + d + 64];
                float k1 = S[r * 256 + d + 128], k2 = S[r * 256 + d + 192];
                qh[(size_t)row_g * 128 + d]      = f2b((q1 * cs - q2 * sn) * qscale);
                qh[(size_t)row_g * 128 + d + 64] = f2b((q2 * cs + q1 * sn) * qscale);
                kh[(size_t)row_g * 128 + d]      = f2b(k1 * cs - k2 * sn);
                kh[(size_t)row_g * 128 + d + 64] = f2b(k2 * cs + k1 * sn);
            }
        }
        return;
    }

    // ---- silu tiles: stage bf16 [e_local][m_local] in LDS (swizzled), ----
    // ---- then write 512B-contiguous rows (uT[e][m] / vT[b][e][l]).     ----
    __syncthreads();
#pragma unroll
    for (int mf = 0; mf < 8; ++mf) {
        int m_l = wm * 128 + mf * 16 + hi * 4;
#pragma unroll
        for (int nf = 0; nf < 4; ++nf) {
            int e_l = wn * 64 + nf * 16 + fr;
            ushort4 pk;
            pk.x = f2b(silu(acc[mf][nf][0]));
            pk.y = f2b(silu(acc[mf][nf][1]));
            pk.z = f2b(silu(acc[mf][nf][2]));
            pk.w = f2b(silu(acc[mf][nf][3]));
            int byte = (e_l * 512 + m_l * 2) ^ ((e_l & 7) << 4);
            *(ushort4*)(smem + byte) = pk;
        }
    }
    __syncthreads();
    int er = tid >> 5;                 // 0..15
    int ch = (tid & 31) * 16;          // byte chunk within 512B row
#pragma unroll
    for (int it = 0; it < 16; ++it) {
        int e_l = it * 16 + er;
        int byte = (e_l * 512 + ch) ^ ((e_l & 7) << 4);
        int4 v = *(const int4*)(smem + byte);
        unsigned short* dst;
        if (bx < 6) {
            dst = uT + (size_t)(col0 + e_l) * Mrows + row0;
        } else {
            int e = col0 + e_l - Edim;
            dst = vT + ((size_t)(row0 >> 8) * Edim + e) * Ltok;
        }
        *(int4*)((char*)dst + ch) = v;
    }
}

// ================= fused attention: softmax(q̂k̂ᵀ) @ V ⊙ u -> o_bf =================
__launch_bounds__(256)
__global__ void fused_attn(const unsigned short* __restrict__ qh,
                           const unsigned short* __restrict__ kh,
                           const unsigned short* __restrict__ vT,
                           const unsigned short* __restrict__ uT,
                           unsigned short* __restrict__ ob) {
    int ec = blockIdx.x, qt = blockIdx.y, b = blockIdx.z;
    int tid  = threadIdx.x;
    int lane = tid & 63, w = tid >> 6;
    int fr = lane & 15, hi = lane >> 4;
    int qbase = b * 256 + qt * 64 + w * 16;

    bf16x8 qf[4];
#pragma unroll
    for (int ks = 0; ks < 4; ++ks)
        qf[ks] = *(const bf16x8*)(qh + (size_t)(qbase + fr) * 128 + ks * 32 + hi * 8);
    f32x4 sacc[16] = {};
#pragma unroll
    for (int mf = 0; mf < 16; ++mf) {
#pragma unroll
        for (int ks = 0; ks < 4; ++ks) {
            bf16x8 kf = *(const bf16x8*)(kh + (size_t)(b * 256 + mf * 16 + fr) * 128 + ks * 32 + hi * 8);
            sacc[mf] = __builtin_amdgcn_mfma_f32_16x16x32_bf16(kf, qf[ks], sacc[mf], 0, 0, 0);
        }
    }

    float mx = -3.4e38f;
#pragma unroll
    for (int mf = 0; mf < 16; ++mf)
#pragma unroll
        for (int j = 0; j < 4; ++j)
            mx = fmaxf(mx, sacc[mf][j]);
    mx = fmaxf(mx, __shfl_xor(mx, 16, 64));
    mx = fmaxf(mx, __shfl_xor(mx, 32, 64));
    float sum = 0.f;
#pragma unroll
    for (int mf = 0; mf < 16; ++mf)
#pragma unroll
        for (int j = 0; j < 4; ++j) {
            float e = expf(sacc[mf][j] - mx);
            sacc[mf][j] = e;
            sum += e;
        }
    sum += __shfl_xor(sum, 16, 64);
    sum += __shfl_xor(sum, 32, 64);
    float inv = 1.0f / sum;

    unsigned int dw[16][2];
#pragma unroll
    for (int mf = 0; mf < 16; ++mf) {
        dw[mf][0] = pk2(sacc[mf][0] * inv, sacc[mf][1] * inv);
        dw[mf][1] = pk2(sacc[mf][2] * inv, sacc[mf][3] * inv);
    }

    int sA = fr + 32 * (hi & 1);
    int sB = sA + 16;
    bool up = (hi >> 1) != 0;
    unsigned int pa[8][4];
#pragma unroll
    for (int ks = 0; ks < 8; ++ks) {
        unsigned int a00 = __shfl((int)dw[2 * ks][0],     sA, 64);
        unsigned int a01 = __shfl((int)dw[2 * ks + 1][0], sA, 64);
        unsigned int a10 = __shfl((int)dw[2 * ks][1],     sA, 64);
        unsigned int a11 = __shfl((int)dw[2 * ks + 1][1], sA, 64);
        unsigned int b00 = __shfl((int)dw[2 * ks][0],     sB, 64);
        unsigned int b01 = __shfl((int)dw[2 * ks + 1][0], sB, 64);
        unsigned int b10 = __shfl((int)dw[2 * ks][1],     sB, 64);
        unsigned int b11 = __shfl((int)dw[2 * ks + 1][1], sB, 64);
        pa[ks][0] = up ? a01 : a00;
        pa[ks][1] = up ? a11 : a10;
        pa[ks][2] = up ? b01 : b00;
        pa[ks][3] = up ? b11 : b10;
    }

    const unsigned short* vb = vT + (size_t)b * Edim * Ltok;
    int e0 = ec * 192;
#pragma unroll 2
    for (int ef = 0; ef < 12; ++ef) {
        int e = e0 + ef * 16 + fr;
        f32x4 oacc = {};
#pragma unroll
        for (int ks = 0; ks < 8; ++ks) {
            bf16x8 vf = *(const bf16x8*)(vb + (size_t)e * Ltok + ks * 32 + hi * 8);
            oacc = __builtin_amdgcn_mfma_f32_16x16x32_bf16(*(const bf16x8*)&pa[ks], vf, oacc, 0, 0, 0);
        }
        ushort4 uv = *(const ushort4*)(uT + (size_t)e * Mrows + qbase + hi * 4);
        ob[(size_t)(qbase + hi * 4 + 0) * Edim + e] = f2b(oacc[0] * b2f(uv.x));
        ob[(size_t)(qbase + hi * 4 + 1) * Edim + e] = f2b(oacc[1] * b2f(uv.y));
        ob[(size_t)(qbase + hi * 4 + 2) * Edim + e] = f2b(oacc[2] * b2f(uv.z));
        ob[(size_t)(qbase + hi * 4 + 3) * Edim + e] = f2b(oacc[3] * b2f(uv.w));
    }
}

// ------ rmsnorm + t_emb bias (entry): h += emb; y = norm(h) -----------------
__global__ void rmsnorm_bias(float* __restrict__ x, const float* __restrict__ t_emb,
                             const int* __restrict__ t_idx, const float* __restrict__ w,
                             unsigned short* __restrict__ y) {
    int r = blockIdx.x * 4 + (threadIdx.x >> 6);
    int lane = threadIdx.x & 63;
    const float* e = t_emb + (size_t)t_idx[r >> 8] * Hdim;
    float* xr = x + (size_t)r * Hdim;
    float4 a = *(const float4*)&xr[lane * 4];
    float4 b = *(const float4*)&xr[lane * 4 + 256];
    float4 c = *(const float4*)&xr[lane * 4 + 512];
    float4 ea = *(const float4*)&e[lane * 4];
    float4 eb = *(const float4*)&e[lane * 4 + 256];
    float4 ec = *(const float4*)&e[lane * 4 + 512];
    a.x += ea.x; a.y += ea.y; a.z += ea.z; a.w += ea.w;
    b.x += eb.x; b.y += eb.y; b.z += eb.z; b.w += eb.w;
    c.x += ec.x; c.y += ec.y; c.z += ec.z; c.w += ec.w;
    *(float4*)&xr[lane * 4]       = a;
    *(float4*)&xr[lane * 4 + 256] = b;
    *(float4*)&xr[lane * 4 + 512] = c;
    float ss = a.x * a.x + a.y * a.y + a.z * a.z + a.w * a.w
             + b.x * b.x + b.y * b.y + b.z * b.z + b.w * b.w
             + c.x * c.x + c.y * c.y + c.z * c.z + c.w * c.w;
#pragma unroll
    for (int o = 1; o < 64; o <<= 1) ss += __shfl_xor(ss, o, 64);
    float s = 1.0f / (sqrtf(ss / (float)Hdim) + 1e-6f);
    float4 wa = *(const float4*)&w[lane * 4];
    float4 wb = *(const float4*)&w[lane * 4 + 256];
    float4 wc = *(const float4*)&w[lane * 4 + 512];
    unsigned short* yr = y + (size_t)r * Hdim;
    ushort4 o0, o1, o2;
    o0.x = f2b(a.x * s * wa.x); o0.y = f2b(a.y * s * wa.y);
    o0.z = f2b(a.z * s * wa.z); o0.w = f2b(a.w * s * wa.w);
    o1.x = f2b(b.x * s * wb.x); o1.y = f2b(b.y * s * wb.y);
    o1.z = f2b(b.z * s * wb.z); o1.w = f2b(b.w * s * wb.w);
    o2.x = f2b(c.x * s * wc.x); o2.y = f2b(c.y * s * wc.y);
    o2.z = f2b(c.z * s * wc.z); o2.w = f2b(c.w * s * wc.w);
    *(ushort4*)&yr[lane * 4]       = o0;
    *(ushort4*)&yr[lane * 4 + 256] = o1;
    *(ushort4*)&yr[lane * 4 + 512] = o2;
}

// ------ rmsnorm with bf16 split-K partial fold: h += Σ p[s]; y = norm(h) ----
__global__ void rmsnorm_acc(float* __restrict__ x, const unsigned short* __restrict__ p,
                            const float* __restrict__ w, unsigned short* __restrict__ y) {
    int r = blockIdx.x * 4 + (threadIdx.x >> 6);
    int lane = threadIdx.x & 63;
    float* xr = x + (size_t)r * Hdim;
    float4 a = *(const float4*)&xr[lane * 4];
    float4 b = *(const float4*)&xr[lane * 4 + 256];
    float4 c = *(const float4*)&xr[lane * 4 + 512];
#pragma unroll
    for (int s = 0; s < 4; ++s) {
        const unsigned short* ps = p + (size_t)(s * Mrows + r) * Hdim;
        ushort4 a0 = *(const ushort4*)&ps[lane * 4];
        ushort4 b0 = *(const ushort4*)&ps[lane * 4 + 256];
        ushort4 c0 = *(const ushort4*)&ps[lane * 4 + 512];
        a.x += b2f(a0.x); a.y += b2f(a0.y); a.z += b2f(a0.z); a.w += b2f(a0.w);
        b.x += b2f(b0.x); b.y += b2f(b0.y); b.z += b2f(b0.z); b.w += b2f(b0.w);
        c.x += b2f(c0.x); c.y += b2f(c0.y); c.z += b2f(c0.z); c.w += b2f(c0.w);
    }
    *(float4*)&xr[lane * 4]       = a;
    *(float4*)&xr[lane * 4 + 256] = b;
    *(float4*)&xr[lane * 4 + 512] = c;
    float ss = a.x * a.x + a.y * a.y + a.z * a.z + a.w * a.w
             + b.x * b.x + b.y * b.y + b.z * b.z + b.w * b.w
             + c.x * c.x + c.y * c.y + c.z * c.z + c.w * c.w;
#pragma unroll
    for (int o = 1; o < 64; o <<= 1) ss += __shfl_xor(ss, o, 64);
    float s = 1.0f / (sqrtf(ss / (float)Hdim) + 1e-6f);
    float4 wa = *(const float4*)&w[lane * 4];
    float4 wb = *(const float4*)&w[lane * 4 + 256];
    float4 wc = *(const float4*)&w[lane * 4 + 512];
    unsigned short* yr = y + (size_t)r * Hdim;
    ushort4 o0, o1, o2;
    o0.x = f2b(a.x * s * wa.x); o0.y = f2b(a.y * s * wa.y);
    o0.z = f2b(a.z * s * wa.z); o0.w = f2b(a.w * s * wa.w);
    o1.x = f2b(b.x * s * wb.x); o1.y = f2b(b.y * s * wb.y);
    o1.z = f2b(b.z * s * wb.z); o1.w = f2b(b.w * s * wb.w);
    o2.x = f2b(c.x * s * wc.x); o2.y = f2b(c.y * s * wc.y);
    o2.z = f2b(c.z * s * wc.z); o2.w = f2b(c.w * s * wc.w);
    *(ushort4*)&yr[lane * 4]       = o0;
    *(ushort4*)&yr[lane * 4 + 256] = o1;
    *(ushort4*)&yr[lane * 4 + 512] = o2;
}

// ---------------- unpatchify ----------------
__global__ void unpatch_kernel(const float* __restrict__ y, float* __restrict__ out) {
    int bc = blockIdx.x;
    int iy = bc & 127;
    int t  = bc >> 7;
    int c  = t % 3;
    int b  = t / 3;
    int ix = threadIdx.x;
    int gy = iy >> 3, py = iy & 7, gx = ix >> 3, px = ix & 7;
    out[((size_t)(b * 3 + c) * IMG + iy) * IMG + ix] =
        y[(size_t)(b * Ltok + gy * 16 + gx) * PDim + (py * 8 + px) * 3 + c];
}

extern "C" void kernel_launch(void* const* d_in, const int* in_sizes, int n_in,
                              void* d_out, int out_size, void* d_ws, size_t ws_size,
                              hipStream_t stream) {
    const float* x        = (const float*)d_in[0];
    const int*   t_idx    = (const int*)  d_in[1];
    const float* patch_W  = (const float*)d_in[2];
    const float* t_emb    = (const float*)d_in[3];
    const float* Wuv      = (const float*)d_in[4];
    const float* Wout     = (const float*)d_in[5];
    const float* gnorm    = (const float*)d_in[6];
    const float* fnorm    = (const float*)d_in[7];
    const float* unpatchW = (const float*)d_in[8];
    float* out = (float*)d_out;

    // ---- workspace layout ----
    char* wsb = (char*)d_ws;
    size_t off = 0;
    auto alloc = [&](size_t bytes) { char* p = wsb + off; off += (bytes + 255) & ~(size_t)255; return p; };
    float* pe   = (float*)alloc(256 * 128 * 4);
    float* h    = (float*)alloc((size_t)Mrows * Hdim * 4);
    float* y    = (float*)alloc((size_t)Mrows * PDim * 4);
    unsigned short* pbuf = (unsigned short*)alloc((size_t)4 * Mrows * Hdim * 2);
    unsigned short* xp   = (unsigned short*)alloc((size_t)Mrows * PDim * 2);
    unsigned short* xn   = (unsigned short*)alloc((size_t)Mrows * Hdim * 2);
    unsigned short* uT   = (unsigned short*)alloc((size_t)Edim * Mrows * 2);
    unsigned short* vT   = (unsigned short*)alloc((size_t)Bsz * Edim * Ltok * 2);
    unsigned short* qh   = (unsigned short*)alloc((size_t)Mrows * 128 * 2);
    unsigned short* kh   = (unsigned short*)alloc((size_t)Mrows * 128 * 2);
    unsigned short* o_bf = (unsigned short*)alloc((size_t)Mrows * Edim * 2);
    unsigned short* WuvT  = (unsigned short*)alloc((size_t)NLAY * UVW * Hdim * 2);
    unsigned short* WoutT = (unsigned short*)alloc((size_t)NLAY * Hdim * Edim * 2);
    unsigned short* patchWT   = (unsigned short*)alloc((size_t)Hdim * PDim * 2);
    unsigned short* unpatchWT = (unsigned short*)alloc((size_t)PDim * Hdim * 2);
    if (off > ws_size) return;   // distinct failure signature (out stays 0)

    pe_kernel<<<256, 128, 0, stream>>>(pe);
    patchify_kernel<<<Bsz * 3 * IMG, IMG, 0, stream>>>(x, xp);

    // weight transposes upfront (batched over layers)
    trans_kernel<<<dim3(Hdim / 32, PDim / 32, 1), dim3(32, 8), 0, stream>>>(
        patch_W, Hdim, 0, patchWT, PDim, 0);
    trans_kernel<<<dim3(PDim / 32, Hdim / 32, 1), dim3(32, 8), 0, stream>>>(
        unpatchW, PDim, 0, unpatchWT, Hdim, 0);
    trans_kernel<<<dim3(UVW / 32, Hdim / 32, NLAY), dim3(32, 8), 0, stream>>>(
        Wuv, UVW, (long long)Hdim * UVW, WuvT, Hdim, (long long)UVW * Hdim);
    trans_kernel<<<dim3(Hdim / 32, Edim / 32, NLAY), dim3(32, 8), 0, stream>>>(
        Wout, Hdim, (long long)Edim * Hdim, WoutT, Edim, (long long)Hdim * Edim);

    gemm_bf16<0><<<(Hdim / 128) * (Mrows / 128), 256, 0, stream>>>(
        xp, PDim, patchWT, PDim, h, Hdim, PDim, Hdim, Hdim / 128);

    rmsnorm_bias<<<Mrows / 4, 256, 0, stream>>>(h, t_emb, t_idx, gnorm, xn);
    for (int l = 0; l < NLAY; ++l) {
        gemm_uvqk8<<<13 * (Mrows / 256), 512, 0, stream>>>(
            xn, WuvT + (size_t)l * UVW * Hdim, uT, vT, qh, kh, pe);
        fused_attn<<<dim3(8, 4, Bsz), 256, 0, stream>>>(qh, kh, vT, uT, o_bf);
        gemm_wout<<<768, 256, 0, stream>>>(
            o_bf, WoutT + (size_t)l * Hdim * Edim, pbuf);
        const float* nw = (l + 1 < NLAY) ? gnorm + (size_t)(l + 1) * Hdim : fnorm;
        rmsnorm_acc<<<Mrows / 4, 256, 0, stream>>>(h, pbuf, nw, xn);
    }

    gemm_bf16<0><<<2 * (Mrows / 128), 256, 0, stream>>>(
        xn, Hdim, unpatchWT, Hdim, y, PDim, Hdim, PDim, 2);
    unpatch_kernel<<<Bsz * 3 * IMG, IMG, 0, stream>>>(y, out);
}